// Round 1
// baseline (3396.885 us; speedup 1.0000x reference)
//
#include <hip/hip_runtime.h>
#include <hip/hip_bf16.h>

#define T_SEQ 1024
#define D_MODEL 768
#define NHEAD 12
#define DKH 64
#define NLAYER 2
#define MCOPY 2
#define HID_DIM 3072
#define VSIZE 32000

// ---------------- embedding gather ----------------
__global__ __launch_bounds__(256) void embed_k(const int* __restrict__ idx,
                                               const float* __restrict__ emb,
                                               float* __restrict__ x) {
  int t = blockIdx.x;
  int r = idx[t];
  for (int d = threadIdx.x; d < D_MODEL; d += 256)
    x[t * D_MODEL + d] = emb[r * D_MODEL + d];
}

// ---------------- rmsnorm ----------------
__global__ __launch_bounds__(256) void rmsnorm_k(const float* __restrict__ x,
                                                 const float* __restrict__ w,
                                                 float* __restrict__ out) {
  int t = blockIdx.x, tid = threadIdx.x;
  const float* row = x + t * D_MODEL;
  float ss = 0.f;
  for (int i = tid; i < D_MODEL; i += 256) { float v = row[i]; ss += v * v; }
  __shared__ float red[256];
  red[tid] = ss; __syncthreads();
  for (int s = 128; s > 0; s >>= 1) {
    if (tid < s) red[tid] += red[tid + s];
    __syncthreads();
  }
  float inv = rsqrtf(red[0] / (float)D_MODEL + 1e-5f);
  for (int i = tid; i < D_MODEL; i += 256)
    out[t * D_MODEL + i] = row[i] * inv * w[i];
}

// ---------------- tiled f32 GEMM: C = A@W (+bias) (+res) ----------------
// A: MxK row-major, W: KxN row-major. M,N,K multiples of 64/16.
__global__ __launch_bounds__(256) void gemm64(const float* __restrict__ A,
                                              const float* __restrict__ W,
                                              const float* __restrict__ bias,
                                              const float* __restrict__ res,
                                              float* __restrict__ C,
                                              int M, int N, int K) {
  __shared__ float As[16][65];
  __shared__ float Bs[16][64];
  int tid = threadIdx.x;
  int tx = tid & 15, ty = tid >> 4;
  int row0 = blockIdx.y * 64, col0 = blockIdx.x * 64;
  float acc[4][4];
  #pragma unroll
  for (int i = 0; i < 4; ++i)
    #pragma unroll
    for (int j = 0; j < 4; ++j) acc[i][j] = 0.f;

  int ar = tid >> 2;          // 0..63
  int akq = (tid & 3) * 4;    // 0,4,8,12
  int bkk = tid >> 4;         // 0..15
  int bcq = (tid & 15) * 4;   // 0..60

  for (int k0 = 0; k0 < K; k0 += 16) {
    float4 av = *(const float4*)&A[(size_t)(row0 + ar) * K + k0 + akq];
    As[akq + 0][ar] = av.x;
    As[akq + 1][ar] = av.y;
    As[akq + 2][ar] = av.z;
    As[akq + 3][ar] = av.w;
    *(float4*)&Bs[bkk][bcq] = *(const float4*)&W[(size_t)(k0 + bkk) * N + col0 + bcq];
    __syncthreads();
    #pragma unroll
    for (int kk = 0; kk < 16; ++kk) {
      float a0 = As[kk][ty * 4 + 0];
      float a1 = As[kk][ty * 4 + 1];
      float a2 = As[kk][ty * 4 + 2];
      float a3 = As[kk][ty * 4 + 3];
      float b0 = Bs[kk][tx * 4 + 0];
      float b1 = Bs[kk][tx * 4 + 1];
      float b2 = Bs[kk][tx * 4 + 2];
      float b3 = Bs[kk][tx * 4 + 3];
      acc[0][0] = fmaf(a0, b0, acc[0][0]); acc[0][1] = fmaf(a0, b1, acc[0][1]);
      acc[0][2] = fmaf(a0, b2, acc[0][2]); acc[0][3] = fmaf(a0, b3, acc[0][3]);
      acc[1][0] = fmaf(a1, b0, acc[1][0]); acc[1][1] = fmaf(a1, b1, acc[1][1]);
      acc[1][2] = fmaf(a1, b2, acc[1][2]); acc[1][3] = fmaf(a1, b3, acc[1][3]);
      acc[2][0] = fmaf(a2, b0, acc[2][0]); acc[2][1] = fmaf(a2, b1, acc[2][1]);
      acc[2][2] = fmaf(a2, b2, acc[2][2]); acc[2][3] = fmaf(a2, b3, acc[2][3]);
      acc[3][0] = fmaf(a3, b0, acc[3][0]); acc[3][1] = fmaf(a3, b1, acc[3][1]);
      acc[3][2] = fmaf(a3, b2, acc[3][2]); acc[3][3] = fmaf(a3, b3, acc[3][3]);
    }
    __syncthreads();
  }
  #pragma unroll
  for (int i = 0; i < 4; ++i) {
    int r = row0 + ty * 4 + i;
    #pragma unroll
    for (int j = 0; j < 4; ++j) {
      int c = col0 + tx * 4 + j;
      float v = acc[i][j];
      if (bias) v += bias[c];
      if (res) v += res[(size_t)r * N + c];
      C[(size_t)r * N + c] = v;
    }
  }
}

// ---------------- RoPE (out-of-place) ----------------
__global__ __launch_bounds__(256) void rope_k(const float* __restrict__ in,
                                              float* __restrict__ out) {
  int t = blockIdx.x;
  for (int w = threadIdx.x; w < NHEAD * 32; w += 256) {
    int h = w >> 5, i = w & 31;
    float theta = powf(10000.0f, -(float)i / 32.0f);
    float fr = (float)t * theta;
    float s, c;
    sincosf(fr, &s, &c);
    float e = in[t * D_MODEL + h * 64 + 2 * i];
    float o = in[t * D_MODEL + h * 64 + 2 * i + 1];
    out[t * D_MODEL + h * 64 + i]      = e * c - o * s;
    out[t * D_MODEL + h * 64 + 32 + i] = e * s + o * c;
  }
}

// ---------------- RACE probs: softmax(tanh(proj)/8 @ protos_T) ----------------
// one thread per (mn, t, l_tab, which). planes: this layer's (MCOPY,64,16).
__global__ __launch_bounds__(256) void race_probs(const float* __restrict__ qr,
                                                  const float* __restrict__ kr,
                                                  const float* __restrict__ planes,
                                                  float* __restrict__ pq,
                                                  float* __restrict__ pk) {
  int gid = blockIdx.x * 256 + threadIdx.x;  // < 24*1024*4*2 = 196608
  int w = gid & 1;
  int l = (gid >> 1) & 3;
  int t = (gid >> 3) & 1023;
  int mn = gid >> 13;  // 0..23
  int m = mn / NHEAD, n = mn % NHEAD;
  const float* row = (w ? qr : kr) + t * D_MODEL + n * 64;
  const float* pl = planes + m * 64 * 16 + l * 4;
  float p0 = 0.f, p1 = 0.f, p2 = 0.f, p3 = 0.f;
  #pragma unroll 8
  for (int d = 0; d < 64; ++d) {
    float rv = row[d];
    const float* pp = pl + d * 16;
    p0 = fmaf(rv, pp[0], p0);
    p1 = fmaf(rv, pp[1], p1);
    p2 = fmaf(rv, pp[2], p2);
    p3 = fmaf(rv, pp[3], p3);
  }
  float t0 = tanhf(p0) * 0.125f;
  float t1 = tanhf(p1) * 0.125f;
  float t2 = tanhf(p2) * 0.125f;
  float t3 = tanhf(p3) * 0.125f;
  float lg[16];
  float mx = -1e30f;
  #pragma unroll
  for (int r = 0; r < 16; ++r) {
    float s = ((r & 8) ? t0 : -t0) + ((r & 4) ? t1 : -t1) +
              ((r & 2) ? t2 : -t2) + ((r & 1) ? t3 : -t3);
    lg[r] = s;
    mx = fmaxf(mx, s);
  }
  float sum = 0.f;
  #pragma unroll
  for (int r = 0; r < 16; ++r) {
    float e = expf(lg[r] - mx);
    lg[r] = e;
    sum += e;
  }
  float inv = 1.f / sum;
  float* dst = (w ? pq : pk) + ((size_t)mn * T_SEQ + t) * 64 + l * 16;
  #pragma unroll
  for (int r = 0; r < 16; ++r) dst[r] = lg[r] * inv;
}

// ---------------- RACE scan + output ----------------
// block per (m,n). threads: d = tid&63, g = tid>>6 (lr group of 16).
// Writes mean-over-copies contribution at the reference's scrambled flat
// index h*65536 + t*64 + d (transpose-then-reshape in the reference).
__global__ __launch_bounds__(256) void race_scan(const float* __restrict__ pk_g,
                                                 const float* __restrict__ pq_g,
                                                 const float* __restrict__ v_g,
                                                 float* __restrict__ ro) {
  int mn = blockIdx.x;  // 0..23
  int n = mn % NHEAD;
  int tid = threadIdx.x;
  int d = tid & 63;
  int g = tid >> 6;
  __shared__ float pk[64], pq[64], vv[64];
  __shared__ float part[4][64];
  float a[16], bp[16];
  #pragma unroll
  for (int i = 0; i < 16; ++i) { a[i] = 0.f; bp[i] = 0.f; }
  const float* pkrow = pk_g + (size_t)mn * T_SEQ * 64;
  const float* pqrow = pq_g + (size_t)mn * T_SEQ * 64;
  for (int t = 0; t < T_SEQ; ++t) {
    if (tid < 64) pk[tid] = pkrow[t * 64 + tid];
    else if (tid < 128) pq[tid - 64] = pqrow[t * 64 + tid - 64];
    else if (tid < 192) vv[tid - 128] = v_g[t * D_MODEL + n * 64 + tid - 128];
    __syncthreads();
    float vd = vv[d];
    float c = 0.f;
    #pragma unroll
    for (int i = 0; i < 16; ++i) {
      int lr = g * 16 + i;
      float p = pk[lr];
      a[i] += p;
      bp[i] = fmaf(p, vd, bp[i]);
      c = fmaf(pq[lr] * bp[i], __builtin_amdgcn_rcpf(a[i] + 1e-6f), c);
    }
    part[g][d] = c;
    __syncthreads();
    if (tid < 64) {
      float s = part[0][tid] + part[1][tid] + part[2][tid] + part[3][tid];
      atomicAdd(&ro[n * (T_SEQ * 64) + t * 64 + tid], 0.5f * s);
    }
  }
}

// ---------------- silu(g1)*g2 (in place on g1) ----------------
__global__ __launch_bounds__(256) void silu_mul_k(float* __restrict__ g1,
                                                  const float* __restrict__ g2) {
  int i = blockIdx.x * 256 + threadIdx.x;
  float a = g1[i];
  float b = g2[i];
  g1[i] = (a / (1.f + expf(-a))) * b;
}

extern "C" void kernel_launch(void* const* d_in, const int* in_sizes, int n_in,
                              void* d_out, int out_size, void* d_ws, size_t ws_size,
                              hipStream_t stream) {
  const int*   in_idx       = (const int*)d_in[0];
  const float* tok_emb      = (const float*)d_in[1];
  const float* norm1_w      = (const float*)d_in[2];
  const float* qw           = (const float*)d_in[3];
  const float* kw           = (const float*)d_in[4];
  const float* vw           = (const float*)d_in[5];
  const float* ow           = (const float*)d_in[6];
  const float* ob           = (const float*)d_in[7];
  const float* norm2_w      = (const float*)d_in[8];
  const float* ff_w1        = (const float*)d_in[9];
  const float* ff_w2        = (const float*)d_in[10];
  const float* ff_w3        = (const float*)d_in[11];
  const float* final_norm_w = (const float*)d_in[12];
  const float* out_w        = (const float*)d_in[13];
  const float* planes       = (const float*)d_in[14];

  float* ws = (float*)d_ws;
  const size_t SZ_TD = (size_t)T_SEQ * D_MODEL;      // 786432
  float* X  = ws;
  float* Hb = X + SZ_TD;
  float* Q  = Hb + SZ_TD;
  float* Kb = Q + SZ_TD;
  float* Vb = Kb + SZ_TD;
  float* QR = Vb + SZ_TD;
  float* KR = QR + SZ_TD;
  float* PK = KR + SZ_TD;                            // 24*1024*64 = 1572864
  float* PQ = PK + (size_t)MCOPY * NHEAD * T_SEQ * 64;
  float* RO = PQ + (size_t)MCOPY * NHEAD * T_SEQ * 64;
  float* G2 = RO + SZ_TD;                            // 1024*3072
  float* G1 = PK;                                    // alias (PK+PQ region, free then)

  embed_k<<<T_SEQ, 256, 0, stream>>>(in_idx, tok_emb, X);

  dim3 g768(D_MODEL / 64, T_SEQ / 64);
  dim3 g3072(HID_DIM / 64, T_SEQ / 64);

  for (int l = 0; l < NLAYER; ++l) {
    rmsnorm_k<<<T_SEQ, 256, 0, stream>>>(X, norm1_w + l * D_MODEL, Hb);
    gemm64<<<g768, 256, 0, stream>>>(Hb, qw + (size_t)l * D_MODEL * D_MODEL, nullptr, nullptr, Q, T_SEQ, D_MODEL, D_MODEL);
    gemm64<<<g768, 256, 0, stream>>>(Hb, kw + (size_t)l * D_MODEL * D_MODEL, nullptr, nullptr, Kb, T_SEQ, D_MODEL, D_MODEL);
    gemm64<<<g768, 256, 0, stream>>>(Hb, vw + (size_t)l * D_MODEL * D_MODEL, nullptr, nullptr, Vb, T_SEQ, D_MODEL, D_MODEL);
    rope_k<<<T_SEQ, 256, 0, stream>>>(Q, QR);
    rope_k<<<T_SEQ, 256, 0, stream>>>(Kb, KR);
    race_probs<<<(MCOPY * NHEAD * T_SEQ * 4 * 2) / 256, 256, 0, stream>>>(
        QR, KR, planes + (size_t)l * MCOPY * 64 * 16, PQ, PK);
    hipMemsetAsync(RO, 0, SZ_TD * sizeof(float), stream);
    race_scan<<<MCOPY * NHEAD, 256, 0, stream>>>(PK, PQ, Vb, RO);
    gemm64<<<g768, 256, 0, stream>>>(RO, ow + (size_t)l * D_MODEL * D_MODEL, ob + l * D_MODEL, X, X, T_SEQ, D_MODEL, D_MODEL);
    rmsnorm_k<<<T_SEQ, 256, 0, stream>>>(X, norm2_w + l * D_MODEL, Hb);
    gemm64<<<g3072, 256, 0, stream>>>(Hb, ff_w1 + (size_t)l * D_MODEL * HID_DIM, nullptr, nullptr, G1, T_SEQ, HID_DIM, D_MODEL);
    gemm64<<<g3072, 256, 0, stream>>>(Hb, ff_w2 + (size_t)l * D_MODEL * HID_DIM, nullptr, nullptr, G2, T_SEQ, HID_DIM, D_MODEL);
    silu_mul_k<<<(T_SEQ * HID_DIM) / 256, 256, 0, stream>>>(G1, G2);
    gemm64<<<g768, 256, 0, stream>>>(G1, ff_w3 + (size_t)l * HID_DIM * D_MODEL, nullptr, X, X, T_SEQ, D_MODEL, HID_DIM);
  }
  rmsnorm_k<<<T_SEQ, 256, 0, stream>>>(X, final_norm_w, Hb);
  dim3 gout(VSIZE / 64, T_SEQ / 64);
  gemm64<<<gout, 256, 0, stream>>>(Hb, out_w, nullptr, nullptr, (float*)d_out, T_SEQ, VSIZE, D_MODEL);
}

// Round 2
// 2038.303 us; speedup vs baseline: 1.6665x; 1.6665x over previous
//
#include <hip/hip_runtime.h>
#include <hip/hip_bf16.h>

#define T_SEQ 1024
#define D_MODEL 768
#define NHEAD 12
#define DKH 64
#define NLAYER 2
#define MCOPY 2
#define HID_DIM 3072
#define VSIZE 32000
#define NCH 32
#define TL 32   // T_SEQ / NCH

// ---------------- embedding gather ----------------
__global__ __launch_bounds__(256) void embed_k(const int* __restrict__ idx,
                                               const float* __restrict__ emb,
                                               float* __restrict__ x) {
  int t = blockIdx.x;
  int r = idx[t];
  for (int d = threadIdx.x; d < D_MODEL; d += 256)
    x[t * D_MODEL + d] = emb[r * D_MODEL + d];
}

// ---------------- rmsnorm ----------------
__global__ __launch_bounds__(256) void rmsnorm_k(const float* __restrict__ x,
                                                 const float* __restrict__ w,
                                                 float* __restrict__ out) {
  int t = blockIdx.x, tid = threadIdx.x;
  const float* row = x + t * D_MODEL;
  float ss = 0.f;
  for (int i = tid; i < D_MODEL; i += 256) { float v = row[i]; ss += v * v; }
  __shared__ float red[256];
  red[tid] = ss; __syncthreads();
  for (int s = 128; s > 0; s >>= 1) {
    if (tid < s) red[tid] += red[tid + s];
    __syncthreads();
  }
  float inv = rsqrtf(red[0] / (float)D_MODEL + 1e-5f);
  for (int i = tid; i < D_MODEL; i += 256)
    out[t * D_MODEL + i] = row[i] * inv * w[i];
}

// ---------------- tiled f32 GEMM: C = A@W (+bias) (+res) ----------------
__global__ __launch_bounds__(256) void gemm64(const float* __restrict__ A,
                                              const float* __restrict__ W,
                                              const float* __restrict__ bias,
                                              const float* __restrict__ res,
                                              float* __restrict__ C,
                                              int M, int N, int K) {
  __shared__ float As[16][65];
  __shared__ float Bs[16][64];
  int tid = threadIdx.x;
  int tx = tid & 15, ty = tid >> 4;
  int row0 = blockIdx.y * 64, col0 = blockIdx.x * 64;
  float acc[4][4];
  #pragma unroll
  for (int i = 0; i < 4; ++i)
    #pragma unroll
    for (int j = 0; j < 4; ++j) acc[i][j] = 0.f;

  int ar = tid >> 2;
  int akq = (tid & 3) * 4;
  int bkk = tid >> 4;
  int bcq = (tid & 15) * 4;

  for (int k0 = 0; k0 < K; k0 += 16) {
    float4 av = *(const float4*)&A[(size_t)(row0 + ar) * K + k0 + akq];
    As[akq + 0][ar] = av.x;
    As[akq + 1][ar] = av.y;
    As[akq + 2][ar] = av.z;
    As[akq + 3][ar] = av.w;
    *(float4*)&Bs[bkk][bcq] = *(const float4*)&W[(size_t)(k0 + bkk) * N + col0 + bcq];
    __syncthreads();
    #pragma unroll
    for (int kk = 0; kk < 16; ++kk) {
      float a0 = As[kk][ty * 4 + 0];
      float a1 = As[kk][ty * 4 + 1];
      float a2 = As[kk][ty * 4 + 2];
      float a3 = As[kk][ty * 4 + 3];
      float b0 = Bs[kk][tx * 4 + 0];
      float b1 = Bs[kk][tx * 4 + 1];
      float b2 = Bs[kk][tx * 4 + 2];
      float b3 = Bs[kk][tx * 4 + 3];
      acc[0][0] = fmaf(a0, b0, acc[0][0]); acc[0][1] = fmaf(a0, b1, acc[0][1]);
      acc[0][2] = fmaf(a0, b2, acc[0][2]); acc[0][3] = fmaf(a0, b3, acc[0][3]);
      acc[1][0] = fmaf(a1, b0, acc[1][0]); acc[1][1] = fmaf(a1, b1, acc[1][1]);
      acc[1][2] = fmaf(a1, b2, acc[1][2]); acc[1][3] = fmaf(a1, b3, acc[1][3]);
      acc[2][0] = fmaf(a2, b0, acc[2][0]); acc[2][1] = fmaf(a2, b1, acc[2][1]);
      acc[2][2] = fmaf(a2, b2, acc[2][2]); acc[2][3] = fmaf(a2, b3, acc[2][3]);
      acc[3][0] = fmaf(a3, b0, acc[3][0]); acc[3][1] = fmaf(a3, b1, acc[3][1]);
      acc[3][2] = fmaf(a3, b2, acc[3][2]); acc[3][3] = fmaf(a3, b3, acc[3][3]);
    }
    __syncthreads();
  }
  #pragma unroll
  for (int i = 0; i < 4; ++i) {
    int r = row0 + ty * 4 + i;
    #pragma unroll
    for (int j = 0; j < 4; ++j) {
      int c = col0 + tx * 4 + j;
      float v = acc[i][j];
      if (bias) v += bias[c];
      if (res) v += res[(size_t)r * N + c];
      C[(size_t)r * N + c] = v;
    }
  }
}

// ---------------- RoPE (out-of-place) ----------------
__global__ __launch_bounds__(256) void rope_k(const float* __restrict__ in,
                                              float* __restrict__ out) {
  int t = blockIdx.x;
  for (int w = threadIdx.x; w < NHEAD * 32; w += 256) {
    int h = w >> 5, i = w & 31;
    float theta = powf(10000.0f, -(float)i / 32.0f);
    float fr = (float)t * theta;
    float s, c;
    sincosf(fr, &s, &c);
    float e = in[t * D_MODEL + h * 64 + 2 * i];
    float o = in[t * D_MODEL + h * 64 + 2 * i + 1];
    out[t * D_MODEL + h * 64 + i]      = e * c - o * s;
    out[t * D_MODEL + h * 64 + 32 + i] = e * s + o * c;
  }
}

// ---------------- RACE probs ----------------
__global__ __launch_bounds__(256) void race_probs(const float* __restrict__ qr,
                                                  const float* __restrict__ kr,
                                                  const float* __restrict__ planes,
                                                  float* __restrict__ pq,
                                                  float* __restrict__ pk) {
  int gid = blockIdx.x * 256 + threadIdx.x;
  int w = gid & 1;
  int l = (gid >> 1) & 3;
  int t = (gid >> 3) & 1023;
  int mn = gid >> 13;
  int m = mn / NHEAD, n = mn % NHEAD;
  const float* row = (w ? qr : kr) + t * D_MODEL + n * 64;
  const float* pl = planes + m * 64 * 16 + l * 4;
  float p0 = 0.f, p1 = 0.f, p2 = 0.f, p3 = 0.f;
  #pragma unroll 8
  for (int d = 0; d < 64; ++d) {
    float rv = row[d];
    const float* pp = pl + d * 16;
    p0 = fmaf(rv, pp[0], p0);
    p1 = fmaf(rv, pp[1], p1);
    p2 = fmaf(rv, pp[2], p2);
    p3 = fmaf(rv, pp[3], p3);
  }
  float t0 = tanhf(p0) * 0.125f;
  float t1 = tanhf(p1) * 0.125f;
  float t2 = tanhf(p2) * 0.125f;
  float t3 = tanhf(p3) * 0.125f;
  float lg[16];
  float mx = -1e30f;
  #pragma unroll
  for (int r = 0; r < 16; ++r) {
    float s = ((r & 8) ? t0 : -t0) + ((r & 4) ? t1 : -t1) +
              ((r & 2) ? t2 : -t2) + ((r & 1) ? t3 : -t3);
    lg[r] = s;
    mx = fmaxf(mx, s);
  }
  float sum = 0.f;
  #pragma unroll
  for (int r = 0; r < 16; ++r) {
    float e = expf(lg[r] - mx);
    lg[r] = e;
    sum += e;
  }
  float inv = 1.f / sum;
  float* dst = (w ? pq : pk) + ((size_t)mn * T_SEQ + t) * 64 + l * 16;
  #pragma unroll
  for (int r = 0; r < 16; ++r) dst[r] = lg[r] * inv;
}

// ---------------- RACE pass 1: per-chunk sums of pk and pk*v ----------------
// grid (24, NCH); tid: d = tid&63, g = tid>>6 (16 lr each).
__global__ __launch_bounds__(256) void race_chunksum(const float* __restrict__ pk_g,
                                                     const float* __restrict__ v_g,
                                                     float* __restrict__ csA,
                                                     float* __restrict__ csB) {
  int mn = blockIdx.x, ch = blockIdx.y;
  int n = mn % NHEAD;
  int tid = threadIdx.x;
  int d = tid & 63, g = tid >> 6;
  __shared__ float pk[64], vv[64];
  float a[16], bp[16];
  #pragma unroll
  for (int i = 0; i < 16; ++i) { a[i] = 0.f; bp[i] = 0.f; }
  const float* pkrow = pk_g + ((size_t)mn * T_SEQ + (size_t)ch * TL) * 64;
  const float* vrow = v_g + (size_t)(ch * TL) * D_MODEL + n * 64;
  for (int t = 0; t < TL; ++t) {
    if (tid < 64) pk[tid] = pkrow[t * 64 + tid];
    else if (tid < 128) vv[tid - 64] = vrow[(size_t)t * D_MODEL + tid - 64];
    __syncthreads();
    float vd = vv[d];
    #pragma unroll
    for (int i = 0; i < 16; ++i) {
      float p = pk[g * 16 + i];
      a[i] += p;
      bp[i] = fmaf(p, vd, bp[i]);
    }
    __syncthreads();
  }
  size_t base = ((size_t)mn * NCH + ch) * 64;
  if (d == 0) {
    #pragma unroll
    for (int i = 0; i < 16; ++i) csA[base + g * 16 + i] = a[i];
  }
  #pragma unroll
  for (int i = 0; i < 16; ++i) csB[(base + g * 16 + i) * 64 + d] = bp[i];
}

// ---------------- RACE pass 2: exclusive scan over chunks (in place) --------
// grid (24, 64 lr), 64 threads (d).
__global__ __launch_bounds__(64) void race_chunkscan(float* __restrict__ csA,
                                                     float* __restrict__ csB) {
  int mn = blockIdx.x, lr = blockIdx.y;
  int d = threadIdx.x;
  float runB = 0.f, runA = 0.f;
  for (int c = 0; c < NCH; ++c) {
    size_t ib = (((size_t)mn * NCH + c) * 64 + lr) * 64 + d;
    float b = csB[ib];
    csB[ib] = runB;
    runB += b;
    if (d == 0) {
      size_t ia = ((size_t)mn * NCH + c) * 64 + lr;
      float av = csA[ia];
      csA[ia] = runA;
      runA += av;
    }
  }
}

// ---------------- RACE pass 3: seeded scan + emit ----------------
// grid (24, NCH). Output at scrambled flat index h*65536 + t*64 + d.
__global__ __launch_bounds__(256) void race_scan_emit(const float* __restrict__ pk_g,
                                                      const float* __restrict__ pq_g,
                                                      const float* __restrict__ v_g,
                                                      const float* __restrict__ csA,
                                                      const float* __restrict__ csB,
                                                      float* __restrict__ ro) {
  int mn = blockIdx.x, ch = blockIdx.y;
  int n = mn % NHEAD;
  int tid = threadIdx.x;
  int d = tid & 63, g = tid >> 6;
  __shared__ float pk[64], pq[64], vv[64];
  __shared__ float part[4][64];
  float a[16], bp[16];
  size_t base = ((size_t)mn * NCH + ch) * 64;
  #pragma unroll
  for (int i = 0; i < 16; ++i) {
    a[i] = csA[base + g * 16 + i];
    bp[i] = csB[(base + g * 16 + i) * 64 + d];
  }
  const float* pkrow = pk_g + ((size_t)mn * T_SEQ + (size_t)ch * TL) * 64;
  const float* pqrow = pq_g + ((size_t)mn * T_SEQ + (size_t)ch * TL) * 64;
  const float* vrow = v_g + (size_t)(ch * TL) * D_MODEL + n * 64;
  for (int t = 0; t < TL; ++t) {
    if (tid < 64) pk[tid] = pkrow[t * 64 + tid];
    else if (tid < 128) pq[tid - 64] = pqrow[t * 64 + tid - 64];
    else if (tid < 192) vv[tid - 128] = vrow[(size_t)t * D_MODEL + tid - 128];
    __syncthreads();
    float vd = vv[d];
    float c = 0.f;
    #pragma unroll
    for (int i = 0; i < 16; ++i) {
      float p = pk[g * 16 + i];
      a[i] += p;
      bp[i] = fmaf(p, vd, bp[i]);
      c = fmaf(pq[g * 16 + i] * bp[i], __builtin_amdgcn_rcpf(a[i] + 1e-6f), c);
    }
    part[g][d] = c;
    __syncthreads();
    if (tid < 64) {
      float s = part[0][tid] + part[1][tid] + part[2][tid] + part[3][tid];
      atomicAdd(&ro[n * (T_SEQ * 64) + (ch * TL + t) * 64 + tid], 0.5f * s);
    }
  }
}

// ---------------- silu(g1)*g2 (in place on g1) ----------------
__global__ __launch_bounds__(256) void silu_mul_k(float* __restrict__ g1,
                                                  const float* __restrict__ g2) {
  int i = blockIdx.x * 256 + threadIdx.x;
  float a = g1[i];
  float b = g2[i];
  g1[i] = (a / (1.f + expf(-a))) * b;
}

extern "C" void kernel_launch(void* const* d_in, const int* in_sizes, int n_in,
                              void* d_out, int out_size, void* d_ws, size_t ws_size,
                              hipStream_t stream) {
  const int*   in_idx       = (const int*)d_in[0];
  const float* tok_emb      = (const float*)d_in[1];
  const float* norm1_w      = (const float*)d_in[2];
  const float* qw           = (const float*)d_in[3];
  const float* kw           = (const float*)d_in[4];
  const float* vw           = (const float*)d_in[5];
  const float* ow           = (const float*)d_in[6];
  const float* ob           = (const float*)d_in[7];
  const float* norm2_w      = (const float*)d_in[8];
  const float* ff_w1        = (const float*)d_in[9];
  const float* ff_w2        = (const float*)d_in[10];
  const float* ff_w3        = (const float*)d_in[11];
  const float* final_norm_w = (const float*)d_in[12];
  const float* out_w        = (const float*)d_in[13];
  const float* planes       = (const float*)d_in[14];

  float* ws = (float*)d_ws;
  const size_t SZ_TD = (size_t)T_SEQ * D_MODEL;      // 786432
  float* X  = ws;
  float* Hb = X + SZ_TD;
  float* Q  = Hb + SZ_TD;
  float* Kb = Q + SZ_TD;
  float* Vb = Kb + SZ_TD;
  float* QR = Vb + SZ_TD;
  float* KR = QR + SZ_TD;
  float* PK = KR + SZ_TD;                            // 24*1024*64
  float* PQ = PK + (size_t)MCOPY * NHEAD * T_SEQ * 64;
  float* RO = PQ + (size_t)MCOPY * NHEAD * T_SEQ * 64;
  float* G2 = RO + SZ_TD;                            // 1024*3072
  float* G1 = PK;                                    // alias: PK/PQ dead during FF
  float* CSB = G2;                                   // alias: 24*32*64*64 == 3145728 == |G2|
  float* CSA = Hb;                                   // alias: Hb dead during RACE phase

  embed_k<<<T_SEQ, 256, 0, stream>>>(in_idx, tok_emb, X);

  dim3 g768(D_MODEL / 64, T_SEQ / 64);
  dim3 g3072(HID_DIM / 64, T_SEQ / 64);

  for (int l = 0; l < NLAYER; ++l) {
    rmsnorm_k<<<T_SEQ, 256, 0, stream>>>(X, norm1_w + l * D_MODEL, Hb);
    gemm64<<<g768, 256, 0, stream>>>(Hb, qw + (size_t)l * D_MODEL * D_MODEL, nullptr, nullptr, Q, T_SEQ, D_MODEL, D_MODEL);
    gemm64<<<g768, 256, 0, stream>>>(Hb, kw + (size_t)l * D_MODEL * D_MODEL, nullptr, nullptr, Kb, T_SEQ, D_MODEL, D_MODEL);
    gemm64<<<g768, 256, 0, stream>>>(Hb, vw + (size_t)l * D_MODEL * D_MODEL, nullptr, nullptr, Vb, T_SEQ, D_MODEL, D_MODEL);
    rope_k<<<T_SEQ, 256, 0, stream>>>(Q, QR);
    rope_k<<<T_SEQ, 256, 0, stream>>>(Kb, KR);
    race_probs<<<(MCOPY * NHEAD * T_SEQ * 4 * 2) / 256, 256, 0, stream>>>(
        QR, KR, planes + (size_t)l * MCOPY * 64 * 16, PQ, PK);
    hipMemsetAsync(RO, 0, SZ_TD * sizeof(float), stream);
    dim3 gscan(MCOPY * NHEAD, NCH);
    race_chunksum<<<gscan, 256, 0, stream>>>(PK, Vb, CSA, CSB);
    dim3 gcs(MCOPY * NHEAD, 64);
    race_chunkscan<<<gcs, 64, 0, stream>>>(CSA, CSB);
    race_scan_emit<<<gscan, 256, 0, stream>>>(PK, PQ, Vb, CSA, CSB, RO);
    gemm64<<<g768, 256, 0, stream>>>(RO, ow + (size_t)l * D_MODEL * D_MODEL, ob + l * D_MODEL, X, X, T_SEQ, D_MODEL, D_MODEL);
    rmsnorm_k<<<T_SEQ, 256, 0, stream>>>(X, norm2_w + l * D_MODEL, Hb);
    gemm64<<<g3072, 256, 0, stream>>>(Hb, ff_w1 + (size_t)l * D_MODEL * HID_DIM, nullptr, nullptr, G1, T_SEQ, HID_DIM, D_MODEL);
    gemm64<<<g3072, 256, 0, stream>>>(Hb, ff_w2 + (size_t)l * D_MODEL * HID_DIM, nullptr, nullptr, G2, T_SEQ, HID_DIM, D_MODEL);
    silu_mul_k<<<(T_SEQ * HID_DIM) / 256, 256, 0, stream>>>(G1, G2);
    gemm64<<<g768, 256, 0, stream>>>(G1, ff_w3 + (size_t)l * HID_DIM * D_MODEL, nullptr, X, X, T_SEQ, D_MODEL, HID_DIM);
  }
  rmsnorm_k<<<T_SEQ, 256, 0, stream>>>(X, final_norm_w, Hb);
  dim3 gout(VSIZE / 64, T_SEQ / 64);
  gemm64<<<gout, 256, 0, stream>>>(Hb, out_w, nullptr, nullptr, (float*)d_out, T_SEQ, VSIZE, D_MODEL);
}

// Round 3
// 1029.810 us; speedup vs baseline: 3.2986x; 1.9793x over previous
//
#include <hip/hip_runtime.h>
#include <hip/hip_bf16.h>

#define T_SEQ 1024
#define D_MODEL 768
#define NHEAD 12
#define DKH 64
#define NLAYER 2
#define MCOPY 2
#define HID_DIM 3072
#define VSIZE 32000
#define NCH 32
#define TL 32   // T_SEQ / NCH

typedef __attribute__((ext_vector_type(8))) short short8;
typedef __attribute__((ext_vector_type(4))) float f32x4;

__device__ __forceinline__ short f2bf(float f) {
  unsigned u = __builtin_bit_cast(unsigned, f);
  u = (u + 0x7FFFu + ((u >> 16) & 1u)) >> 16;   // RNE
  return (short)u;
}

// ---------------- embedding gather ----------------
__global__ __launch_bounds__(256) void embed_k(const int* __restrict__ idx,
                                               const float* __restrict__ emb,
                                               float* __restrict__ x) {
  int t = blockIdx.x;
  int r = idx[t];
  for (int d = threadIdx.x; d < D_MODEL; d += 256)
    x[t * D_MODEL + d] = emb[r * D_MODEL + d];
}

// ---------------- rmsnorm ----------------
__global__ __launch_bounds__(256) void rmsnorm_k(const float* __restrict__ x,
                                                 const float* __restrict__ w,
                                                 float* __restrict__ out) {
  int t = blockIdx.x, tid = threadIdx.x;
  const float* row = x + t * D_MODEL;
  float ss = 0.f;
  for (int i = tid; i < D_MODEL; i += 256) { float v = row[i]; ss += v * v; }
  __shared__ float red[256];
  red[tid] = ss; __syncthreads();
  for (int s = 128; s > 0; s >>= 1) {
    if (tid < s) red[tid] += red[tid + s];
    __syncthreads();
  }
  float inv = rsqrtf(red[0] / (float)D_MODEL + 1e-5f);
  for (int i = tid; i < D_MODEL; i += 256)
    out[t * D_MODEL + i] = row[i] * inv * w[i];
}

// ---------------- weight transpose + f32->bf16: W[K][N] -> WT[N][K] ---------
__global__ __launch_bounds__(256) void transpose_cvt(const float* __restrict__ W,
                                                     short* __restrict__ WT,
                                                     int K, int N) {
  __shared__ float tile[32][33];
  int tx = threadIdx.x, ty = threadIdx.y;     // block (32,8)
  int n0 = blockIdx.x * 32, k0 = blockIdx.y * 32;
  #pragma unroll
  for (int i = 0; i < 4; ++i)
    tile[ty + 8 * i][tx] = W[(size_t)(k0 + ty + 8 * i) * N + n0 + tx];
  __syncthreads();
  #pragma unroll
  for (int i = 0; i < 4; ++i)
    WT[(size_t)(n0 + ty + 8 * i) * K + k0 + tx] = f2bf(tile[tx][ty + 8 * i]);
}

// ---------------- bf16 MFMA GEMM: C = A(f32)@Bt^T (+bias)(+res) ----------
// A: [M][K] f32 row-major. Bt: [N][K] bf16 (i.e. W transposed). 128x128 tile.
__global__ __launch_bounds__(256) void gemm_mfma(const float* __restrict__ A,
                                                 const short* __restrict__ Bt,
                                                 const float* __restrict__ bias,
                                                 const float* __restrict__ res,
                                                 float* __restrict__ C,
                                                 int M, int N, int K) {
  __shared__ short As[128][40];   // 80B rows: 16B-aligned, conflict-free b128
  __shared__ short Bs[128][40];
  int tid = threadIdx.x;
  int lane = tid & 63;
  int wave = tid >> 6;
  int wr = wave >> 1, wc = wave & 1;
  int row0 = blockIdx.x * 128, col0 = blockIdx.y * 128;

  f32x4 acc[4][4] = {};

  int srow = tid >> 1;
  int skh = (tid & 1) * 16;
  const float* aSrc = A + (size_t)(row0 + srow) * K + skh;
  const short* bSrc = Bt + (size_t)(col0 + srow) * K + skh;

  int l15 = lane & 15;
  int kg = (lane >> 4) * 8;

  for (int k0 = 0; k0 < K; k0 += 32) {
    float4 a0 = *(const float4*)(aSrc + k0 + 0);
    float4 a1 = *(const float4*)(aSrc + k0 + 4);
    float4 a2 = *(const float4*)(aSrc + k0 + 8);
    float4 a3 = *(const float4*)(aSrc + k0 + 12);
    short8 ap0, ap1;
    ap0[0] = f2bf(a0.x); ap0[1] = f2bf(a0.y); ap0[2] = f2bf(a0.z); ap0[3] = f2bf(a0.w);
    ap0[4] = f2bf(a1.x); ap0[5] = f2bf(a1.y); ap0[6] = f2bf(a1.z); ap0[7] = f2bf(a1.w);
    ap1[0] = f2bf(a2.x); ap1[1] = f2bf(a2.y); ap1[2] = f2bf(a2.z); ap1[3] = f2bf(a2.w);
    ap1[4] = f2bf(a3.x); ap1[5] = f2bf(a3.y); ap1[6] = f2bf(a3.z); ap1[7] = f2bf(a3.w);
    short8 b0 = *(const short8*)(bSrc + k0);
    short8 b1 = *(const short8*)(bSrc + k0 + 8);
    *(short8*)&As[srow][skh] = ap0;
    *(short8*)&As[srow][skh + 8] = ap1;
    *(short8*)&Bs[srow][skh] = b0;
    *(short8*)&Bs[srow][skh + 8] = b1;
    __syncthreads();
    short8 af[4], bf[4];
    #pragma unroll
    for (int m = 0; m < 4; ++m)
      af[m] = *(const short8*)&As[wr * 64 + m * 16 + l15][kg];
    #pragma unroll
    for (int n = 0; n < 4; ++n)
      bf[n] = *(const short8*)&Bs[wc * 64 + n * 16 + l15][kg];
    #pragma unroll
    for (int m = 0; m < 4; ++m)
      #pragma unroll
      for (int n = 0; n < 4; ++n)
        acc[m][n] = __builtin_amdgcn_mfma_f32_16x16x32_bf16(af[m], bf[n], acc[m][n], 0, 0, 0);
    __syncthreads();
  }

  int rbase = (lane >> 4) * 4;
  #pragma unroll
  for (int n = 0; n < 4; ++n) {
    int col = col0 + wc * 64 + n * 16 + l15;
    float bv = bias ? bias[col] : 0.f;
    #pragma unroll
    for (int m = 0; m < 4; ++m) {
      #pragma unroll
      for (int r = 0; r < 4; ++r) {
        int row = row0 + wr * 64 + m * 16 + rbase + r;
        float v = acc[m][n][r] + bv;
        if (res) v += res[(size_t)row * N + col];
        C[(size_t)row * N + col] = v;
      }
    }
  }
}

// ---------------- RoPE (out-of-place) ----------------
__global__ __launch_bounds__(256) void rope_k(const float* __restrict__ in,
                                              float* __restrict__ out) {
  int t = blockIdx.x;
  for (int w = threadIdx.x; w < NHEAD * 32; w += 256) {
    int h = w >> 5, i = w & 31;
    float theta = powf(10000.0f, -(float)i / 32.0f);
    float fr = (float)t * theta;
    float s, c;
    sincosf(fr, &s, &c);
    float e = in[t * D_MODEL + h * 64 + 2 * i];
    float o = in[t * D_MODEL + h * 64 + 2 * i + 1];
    out[t * D_MODEL + h * 64 + i]      = e * c - o * s;
    out[t * D_MODEL + h * 64 + 32 + i] = e * s + o * c;
  }
}

// ---------------- RACE probs ----------------
__global__ __launch_bounds__(256) void race_probs(const float* __restrict__ qr,
                                                  const float* __restrict__ kr,
                                                  const float* __restrict__ planes,
                                                  float* __restrict__ pq,
                                                  float* __restrict__ pk) {
  int gid = blockIdx.x * 256 + threadIdx.x;
  int w = gid & 1;
  int l = (gid >> 1) & 3;
  int t = (gid >> 3) & 1023;
  int mn = gid >> 13;
  int m = mn / NHEAD, n = mn % NHEAD;
  const float* row = (w ? qr : kr) + t * D_MODEL + n * 64;
  const float* pl = planes + m * 64 * 16 + l * 4;
  float p0 = 0.f, p1 = 0.f, p2 = 0.f, p3 = 0.f;
  #pragma unroll 8
  for (int d = 0; d < 64; ++d) {
    float rv = row[d];
    const float* pp = pl + d * 16;
    p0 = fmaf(rv, pp[0], p0);
    p1 = fmaf(rv, pp[1], p1);
    p2 = fmaf(rv, pp[2], p2);
    p3 = fmaf(rv, pp[3], p3);
  }
  float t0 = tanhf(p0) * 0.125f;
  float t1 = tanhf(p1) * 0.125f;
  float t2 = tanhf(p2) * 0.125f;
  float t3 = tanhf(p3) * 0.125f;
  float lg[16];
  float mx = -1e30f;
  #pragma unroll
  for (int r = 0; r < 16; ++r) {
    float s = ((r & 8) ? t0 : -t0) + ((r & 4) ? t1 : -t1) +
              ((r & 2) ? t2 : -t2) + ((r & 1) ? t3 : -t3);
    lg[r] = s;
    mx = fmaxf(mx, s);
  }
  float sum = 0.f;
  #pragma unroll
  for (int r = 0; r < 16; ++r) {
    float e = expf(lg[r] - mx);
    lg[r] = e;
    sum += e;
  }
  float inv = 1.f / sum;
  float* dst = (w ? pq : pk) + ((size_t)mn * T_SEQ + t) * 64 + l * 16;
  #pragma unroll
  for (int r = 0; r < 16; ++r) dst[r] = lg[r] * inv;
}

// ---------------- RACE pass 1: per-chunk sums of pk and pk*v ----------------
__global__ __launch_bounds__(256) void race_chunksum(const float* __restrict__ pk_g,
                                                     const float* __restrict__ v_g,
                                                     float* __restrict__ csA,
                                                     float* __restrict__ csB) {
  int mn = blockIdx.x, ch = blockIdx.y;
  int n = mn % NHEAD;
  int tid = threadIdx.x;
  int d = tid & 63, g = tid >> 6;
  __shared__ float pk[64], vv[64];
  float a[16], bp[16];
  #pragma unroll
  for (int i = 0; i < 16; ++i) { a[i] = 0.f; bp[i] = 0.f; }
  const float* pkrow = pk_g + ((size_t)mn * T_SEQ + (size_t)ch * TL) * 64;
  const float* vrow = v_g + (size_t)(ch * TL) * D_MODEL + n * 64;
  for (int t = 0; t < TL; ++t) {
    if (tid < 64) pk[tid] = pkrow[t * 64 + tid];
    else if (tid < 128) vv[tid - 64] = vrow[(size_t)t * D_MODEL + tid - 64];
    __syncthreads();
    float vd = vv[d];
    #pragma unroll
    for (int i = 0; i < 16; ++i) {
      float p = pk[g * 16 + i];
      a[i] += p;
      bp[i] = fmaf(p, vd, bp[i]);
    }
    __syncthreads();
  }
  size_t base = ((size_t)mn * NCH + ch) * 64;
  if (d == 0) {
    #pragma unroll
    for (int i = 0; i < 16; ++i) csA[base + g * 16 + i] = a[i];
  }
  #pragma unroll
  for (int i = 0; i < 16; ++i) csB[(base + g * 16 + i) * 64 + d] = bp[i];
}

// ---------------- RACE pass 2: exclusive scan over chunks (in place) --------
__global__ __launch_bounds__(64) void race_chunkscan(float* __restrict__ csA,
                                                     float* __restrict__ csB) {
  int mn = blockIdx.x, lr = blockIdx.y;
  int d = threadIdx.x;
  float runB = 0.f, runA = 0.f;
  for (int c = 0; c < NCH; ++c) {
    size_t ib = (((size_t)mn * NCH + c) * 64 + lr) * 64 + d;
    float b = csB[ib];
    csB[ib] = runB;
    runB += b;
    if (d == 0) {
      size_t ia = ((size_t)mn * NCH + c) * 64 + lr;
      float av = csA[ia];
      csA[ia] = runA;
      runA += av;
    }
  }
}

// ---------------- RACE pass 3: seeded scan + emit ----------------
__global__ __launch_bounds__(256) void race_scan_emit(const float* __restrict__ pk_g,
                                                      const float* __restrict__ pq_g,
                                                      const float* __restrict__ v_g,
                                                      const float* __restrict__ csA,
                                                      const float* __restrict__ csB,
                                                      float* __restrict__ ro) {
  int mn = blockIdx.x, ch = blockIdx.y;
  int n = mn % NHEAD;
  int tid = threadIdx.x;
  int d = tid & 63, g = tid >> 6;
  __shared__ float pk[64], pq[64], vv[64];
  __shared__ float part[4][64];
  float a[16], bp[16];
  size_t base = ((size_t)mn * NCH + ch) * 64;
  #pragma unroll
  for (int i = 0; i < 16; ++i) {
    a[i] = csA[base + g * 16 + i];
    bp[i] = csB[(base + g * 16 + i) * 64 + d];
  }
  const float* pkrow = pk_g + ((size_t)mn * T_SEQ + (size_t)ch * TL) * 64;
  const float* pqrow = pq_g + ((size_t)mn * T_SEQ + (size_t)ch * TL) * 64;
  const float* vrow = v_g + (size_t)(ch * TL) * D_MODEL + n * 64;
  for (int t = 0; t < TL; ++t) {
    if (tid < 64) pk[tid] = pkrow[t * 64 + tid];
    else if (tid < 128) pq[tid - 64] = pqrow[t * 64 + tid - 64];
    else if (tid < 192) vv[tid - 128] = vrow[(size_t)t * D_MODEL + tid - 128];
    __syncthreads();
    float vd = vv[d];
    float c = 0.f;
    #pragma unroll
    for (int i = 0; i < 16; ++i) {
      float p = pk[g * 16 + i];
      a[i] += p;
      bp[i] = fmaf(p, vd, bp[i]);
      c = fmaf(pq[g * 16 + i] * bp[i], __builtin_amdgcn_rcpf(a[i] + 1e-6f), c);
    }
    part[g][d] = c;
    __syncthreads();
    if (tid < 64) {
      float s = part[0][tid] + part[1][tid] + part[2][tid] + part[3][tid];
      atomicAdd(&ro[n * (T_SEQ * 64) + (ch * TL + t) * 64 + tid], 0.5f * s);
    }
  }
}

// ---------------- silu(g1)*g2 (in place on g1) ----------------
__global__ __launch_bounds__(256) void silu_mul_k(float* __restrict__ g1,
                                                  const float* __restrict__ g2) {
  int i = blockIdx.x * 256 + threadIdx.x;
  float a = g1[i];
  float b = g2[i];
  g1[i] = (a / (1.f + expf(-a))) * b;
}

extern "C" void kernel_launch(void* const* d_in, const int* in_sizes, int n_in,
                              void* d_out, int out_size, void* d_ws, size_t ws_size,
                              hipStream_t stream) {
  const int*   in_idx       = (const int*)d_in[0];
  const float* tok_emb      = (const float*)d_in[1];
  const float* norm1_w      = (const float*)d_in[2];
  const float* qw           = (const float*)d_in[3];
  const float* kw           = (const float*)d_in[4];
  const float* vw           = (const float*)d_in[5];
  const float* ow           = (const float*)d_in[6];
  const float* ob           = (const float*)d_in[7];
  const float* norm2_w      = (const float*)d_in[8];
  const float* ff_w1        = (const float*)d_in[9];
  const float* ff_w2        = (const float*)d_in[10];
  const float* ff_w3        = (const float*)d_in[11];
  const float* final_norm_w = (const float*)d_in[12];
  const float* out_w        = (const float*)d_in[13];
  const float* planes       = (const float*)d_in[14];

  float* ws = (float*)d_ws;
  const size_t SZ_TD = (size_t)T_SEQ * D_MODEL;      // 786432
  float* X  = ws;
  float* Hb = X + SZ_TD;
  float* Q  = Hb + SZ_TD;
  float* Kb = Q + SZ_TD;
  float* Vb = Kb + SZ_TD;
  float* QR = Vb + SZ_TD;
  float* KR = QR + SZ_TD;
  float* PK = KR + SZ_TD;                            // 24*1024*64
  float* PQ = PK + (size_t)MCOPY * NHEAD * T_SEQ * 64;
  float* RO = PQ + (size_t)MCOPY * NHEAD * T_SEQ * 64;
  float* G2 = RO + SZ_TD;                            // 1024*3072
  float* G1 = PK;                                    // alias: PK/PQ dead during FF
  float* CSB = G2;                                   // alias: 24*32*64*64 == |G2|
  float* CSA = Hb;                                   // alias: Hb dead during RACE

  // bf16 transposed weights region (after f32 region)
  short* WB = (short*)(G2 + (size_t)T_SEQ * HID_DIM);
  const size_t SQ_W  = (size_t)D_MODEL * D_MODEL;    // 589824
  const size_t FF_W  = (size_t)D_MODEL * HID_DIM;    // 2359296
  const size_t LAYER_W = 4 * SQ_W + 3 * FF_W;        // 9437184
  short* qwT[NLAYER]; short* kwT[NLAYER]; short* vwT[NLAYER]; short* owT[NLAYER];
  short* f1T[NLAYER]; short* f2T[NLAYER]; short* f3T[NLAYER];
  for (int l = 0; l < NLAYER; ++l) {
    short* base = WB + l * LAYER_W;
    qwT[l] = base;
    kwT[l] = base + SQ_W;
    vwT[l] = base + 2 * SQ_W;
    owT[l] = base + 3 * SQ_W;
    f1T[l] = base + 4 * SQ_W;
    f2T[l] = base + 4 * SQ_W + FF_W;
    f3T[l] = base + 4 * SQ_W + 2 * FF_W;
  }
  short* outT = WB + NLAYER * LAYER_W;               // [32000][768]

  dim3 tb(32, 8);
  for (int l = 0; l < NLAYER; ++l) {
    transpose_cvt<<<dim3(D_MODEL / 32, D_MODEL / 32), tb, 0, stream>>>(qw + l * SQ_W, qwT[l], D_MODEL, D_MODEL);
    transpose_cvt<<<dim3(D_MODEL / 32, D_MODEL / 32), tb, 0, stream>>>(kw + l * SQ_W, kwT[l], D_MODEL, D_MODEL);
    transpose_cvt<<<dim3(D_MODEL / 32, D_MODEL / 32), tb, 0, stream>>>(vw + l * SQ_W, vwT[l], D_MODEL, D_MODEL);
    transpose_cvt<<<dim3(D_MODEL / 32, D_MODEL / 32), tb, 0, stream>>>(ow + l * SQ_W, owT[l], D_MODEL, D_MODEL);
    transpose_cvt<<<dim3(HID_DIM / 32, D_MODEL / 32), tb, 0, stream>>>(ff_w1 + l * FF_W, f1T[l], D_MODEL, HID_DIM);
    transpose_cvt<<<dim3(HID_DIM / 32, D_MODEL / 32), tb, 0, stream>>>(ff_w2 + l * FF_W, f2T[l], D_MODEL, HID_DIM);
    transpose_cvt<<<dim3(D_MODEL / 32, HID_DIM / 32), tb, 0, stream>>>(ff_w3 + l * FF_W, f3T[l], HID_DIM, D_MODEL);
  }
  transpose_cvt<<<dim3(VSIZE / 32, D_MODEL / 32), tb, 0, stream>>>(out_w, outT, D_MODEL, VSIZE);

  embed_k<<<T_SEQ, 256, 0, stream>>>(in_idx, tok_emb, X);

  dim3 gQ(T_SEQ / 128, D_MODEL / 128);   // (8,6)
  dim3 gF(T_SEQ / 128, HID_DIM / 128);   // (8,24)
  dim3 gO(T_SEQ / 128, VSIZE / 128);     // (8,250)

  for (int l = 0; l < NLAYER; ++l) {
    rmsnorm_k<<<T_SEQ, 256, 0, stream>>>(X, norm1_w + l * D_MODEL, Hb);
    gemm_mfma<<<gQ, 256, 0, stream>>>(Hb, qwT[l], nullptr, nullptr, Q, T_SEQ, D_MODEL, D_MODEL);
    gemm_mfma<<<gQ, 256, 0, stream>>>(Hb, kwT[l], nullptr, nullptr, Kb, T_SEQ, D_MODEL, D_MODEL);
    gemm_mfma<<<gQ, 256, 0, stream>>>(Hb, vwT[l], nullptr, nullptr, Vb, T_SEQ, D_MODEL, D_MODEL);
    rope_k<<<T_SEQ, 256, 0, stream>>>(Q, QR);
    rope_k<<<T_SEQ, 256, 0, stream>>>(Kb, KR);
    race_probs<<<(MCOPY * NHEAD * T_SEQ * 4 * 2) / 256, 256, 0, stream>>>(
        QR, KR, planes + (size_t)l * MCOPY * 64 * 16, PQ, PK);
    hipMemsetAsync(RO, 0, SZ_TD * sizeof(float), stream);
    dim3 gscan(MCOPY * NHEAD, NCH);
    race_chunksum<<<gscan, 256, 0, stream>>>(PK, Vb, CSA, CSB);
    dim3 gcs(MCOPY * NHEAD, 64);
    race_chunkscan<<<gcs, 64, 0, stream>>>(CSA, CSB);
    race_scan_emit<<<gscan, 256, 0, stream>>>(PK, PQ, Vb, CSA, CSB, RO);
    gemm_mfma<<<gQ, 256, 0, stream>>>(RO, owT[l], ob + l * D_MODEL, X, X, T_SEQ, D_MODEL, D_MODEL);
    rmsnorm_k<<<T_SEQ, 256, 0, stream>>>(X, norm2_w + l * D_MODEL, Hb);
    gemm_mfma<<<gF, 256, 0, stream>>>(Hb, f1T[l], nullptr, nullptr, G1, T_SEQ, HID_DIM, D_MODEL);
    gemm_mfma<<<gF, 256, 0, stream>>>(Hb, f2T[l], nullptr, nullptr, G2, T_SEQ, HID_DIM, D_MODEL);
    silu_mul_k<<<(T_SEQ * HID_DIM) / 256, 256, 0, stream>>>(G1, G2);
    gemm_mfma<<<gQ, 256, 0, stream>>>(G1, f3T[l], nullptr, X, X, T_SEQ, D_MODEL, HID_DIM);
  }
  rmsnorm_k<<<T_SEQ, 256, 0, stream>>>(X, final_norm_w, Hb);
  gemm_mfma<<<gO, 256, 0, stream>>>(Hb, outT, nullptr, nullptr, (float*)d_out, T_SEQ, VSIZE, D_MODEL);
}

// Round 4
// 680.007 us; speedup vs baseline: 4.9954x; 1.5144x over previous
//
#include <hip/hip_runtime.h>
#include <hip/hip_bf16.h>

#define T_SEQ 1024
#define D_MODEL 768
#define QKVW 2304
#define NHEAD 12
#define NLAYER 2
#define MCOPY 2
#define HID_DIM 3072
#define VSIZE 32000
#define NCH 32
#define TL 32

typedef __attribute__((ext_vector_type(8))) short short8;
typedef __attribute__((ext_vector_type(4))) float f32x4;

__device__ __forceinline__ short f2bf(float f) {
  unsigned u = __builtin_bit_cast(unsigned, f);
  u = (u + 0x7FFFu + ((u >> 16) & 1u)) >> 16;   // RNE
  return (short)u;
}

// ---------------- sin/cos table: stc[t][i] = (cos, sin) ----------------
__global__ __launch_bounds__(64) void stc_k(float* __restrict__ stc) {
  int t = blockIdx.x;
  int i = threadIdx.x;
  if (i < 32) {
    float theta = powf(10000.0f, -(float)i / 32.0f);
    float s, c;
    sincosf((float)t * theta, &s, &c);
    stc[t * 64 + 2 * i] = c;
    stc[t * 64 + 2 * i + 1] = s;
  }
}

// ---------------- embedding gather ----------------
__global__ __launch_bounds__(256) void embed_k(const int* __restrict__ idx,
                                               const float* __restrict__ emb,
                                               float* __restrict__ x) {
  int t = blockIdx.x;
  int r = idx[t];
  for (int d = threadIdx.x; d < D_MODEL; d += 256)
    x[t * D_MODEL + d] = emb[r * D_MODEL + d];
}

// ---------------- rmsnorm -> bf16 ----------------
__global__ __launch_bounds__(256) void rmsnorm_k(const float* __restrict__ x,
                                                 const float* __restrict__ w,
                                                 short* __restrict__ out) {
  int t = blockIdx.x, tid = threadIdx.x;
  const float* row = x + t * D_MODEL;
  float ss = 0.f;
  for (int i = tid; i < D_MODEL; i += 256) { float v = row[i]; ss += v * v; }
  __shared__ float red[256];
  red[tid] = ss; __syncthreads();
  for (int s = 128; s > 0; s >>= 1) {
    if (tid < s) red[tid] += red[tid + s];
    __syncthreads();
  }
  float inv = rsqrtf(red[0] / (float)D_MODEL + 1e-5f);
  for (int i = tid; i < D_MODEL; i += 256)
    out[t * D_MODEL + i] = f2bf(row[i] * inv * w[i]);
}

// ---------------- weight transpose + f32->bf16: W[K][N] -> WT[N][K] ---------
__global__ __launch_bounds__(256) void transpose_cvt(const float* __restrict__ W,
                                                     short* __restrict__ WT,
                                                     int K, int N) {
  __shared__ float tile[32][33];
  int tx = threadIdx.x, ty = threadIdx.y;     // block (32,8)
  int n0 = blockIdx.x * 32, k0 = blockIdx.y * 32;
  #pragma unroll
  for (int i = 0; i < 4; ++i)
    tile[ty + 8 * i][tx] = W[(size_t)(k0 + ty + 8 * i) * N + n0 + tx];
  __syncthreads();
  #pragma unroll
  for (int i = 0; i < 4; ++i)
    WT[(size_t)(n0 + ty + 8 * i) * K + k0 + tx] = f2bf(tile[tx][ty + 8 * i]);
}

// ---------------- bf16 MFMA GEMM: C = A@Bt^T (+bias)(+res) ----------------
// A: [M=1024][K] bf16. Bt: [N][K] bf16. 128x128 tile, BK=64, 4 waves.
// LDS swizzle: slot ^= (row&7), applied on global source (linear gload_lds
// dest) and on ds_read -> conflict-free b128 (G4 pattern). XCD-bijective
// block swizzle; row-tile fast so one B-panel's 8 blocks share an XCD L2.
__device__ __forceinline__ void stage_tile(const short* __restrict__ gbase,
                                           int ldK, short* lds, int tid) {
  #pragma unroll
  for (int j = 0; j < 4; ++j) {
    int r = j * 32 + (tid >> 3);
    int s = tid & 7;
    const short* gp = gbase + (size_t)r * ldK + (((s ^ (r & 7))) << 3);
    short* lp = lds + j * 2048 + tid * 8;
    __builtin_amdgcn_global_load_lds((const __attribute__((address_space(1))) void*)gp,
                                     (__attribute__((address_space(3))) void*)lp,
                                     16, 0, 0);
  }
}

__device__ __forceinline__ short8 frag_ld(const short* lds, int row, int sl) {
  return *(const short8*)(lds + row * 64 + ((sl ^ (row & 7)) << 3));
}

__global__ __launch_bounds__(256) void gemm_bf16(const short* __restrict__ A,
                                                 const short* __restrict__ Bt,
                                                 const float* __restrict__ bias,
                                                 const float* __restrict__ res,
                                                 float* __restrict__ C,
                                                 int N, int K) {
  __shared__ short As[128 * 64];
  __shared__ short Bs[128 * 64];
  int tid = threadIdx.x;
  int lane = tid & 63;
  int wave = tid >> 6;
  int wr = wave >> 1, wc = wave & 1;
  int l15 = lane & 15, kg = lane >> 4;

  // XCD-bijective swizzle (gridDim.x always divisible by 8)
  int cpx = gridDim.x >> 3;
  int wg = (blockIdx.x & 7) * cpx + (blockIdx.x >> 3);
  int row0 = (wg & 7) * 128;        // M = 1024 always
  int col0 = (wg >> 3) * 128;

  f32x4 acc[4][4] = {};

  for (int k0 = 0; k0 < K; k0 += 64) {
    stage_tile(A + (size_t)row0 * K + k0, K, As, tid);
    stage_tile(Bt + (size_t)col0 * K + k0, K, Bs, tid);
    __syncthreads();
    #pragma unroll
    for (int kk = 0; kk < 2; ++kk) {
      short8 af[4], bf4[4];
      #pragma unroll
      for (int m = 0; m < 4; ++m)
        af[m] = frag_ld(As, wr * 64 + m * 16 + l15, 4 * kk + kg);
      #pragma unroll
      for (int n = 0; n < 4; ++n)
        bf4[n] = frag_ld(Bs, wc * 64 + n * 16 + l15, 4 * kk + kg);
      #pragma unroll
      for (int m = 0; m < 4; ++m)
        #pragma unroll
        for (int n = 0; n < 4; ++n)
          acc[m][n] = __builtin_amdgcn_mfma_f32_16x16x32_bf16(af[m], bf4[n], acc[m][n], 0, 0, 0);
    }
    __syncthreads();
  }

  int rbase = (lane >> 4) * 4;
  #pragma unroll
  for (int n = 0; n < 4; ++n) {
    int col = col0 + wc * 64 + n * 16 + l15;
    float bv = bias ? bias[col] : 0.f;
    #pragma unroll
    for (int m = 0; m < 4; ++m) {
      #pragma unroll
      for (int r = 0; r < 4; ++r) {
        int row = row0 + wr * 64 + m * 16 + rbase + r;
        float v = acc[m][n][r] + bv;
        if (res) v += res[(size_t)row * N + col];
        C[(size_t)row * N + col] = v;
      }
    }
  }
}

// ---------------- RACE probs with fused RoPE ----------------
// thread per (mn, t, l_tab, which). qkv: [1024][2304] (Q|K|V).
__global__ __launch_bounds__(256) void race_probs(const float* __restrict__ qkv,
                                                  const float* __restrict__ stc,
                                                  const float* __restrict__ planes,
                                                  float* __restrict__ pq,
                                                  float* __restrict__ pk) {
  int gid = blockIdx.x * 256 + threadIdx.x;
  int w = gid & 1;
  int l = (gid >> 1) & 3;
  int t = (gid >> 3) & 1023;
  int mn = gid >> 13;
  int m = mn / NHEAD, n = mn % NHEAD;
  const float* raw = qkv + (size_t)t * QKVW + (w ? 0 : D_MODEL) + n * 64;
  const float* sc = stc + t * 64;
  const float* pl = planes + m * 64 * 16 + l * 4;
  float p0 = 0.f, p1 = 0.f, p2 = 0.f, p3 = 0.f;
  #pragma unroll 4
  for (int i = 0; i < 32; ++i) {
    float e = raw[2 * i], o = raw[2 * i + 1];
    float c = sc[2 * i], s = sc[2 * i + 1];
    float re = e * c - o * s;
    float ro = e * s + o * c;
    const float* pe = pl + i * 16;
    const float* po = pl + (i + 32) * 16;
    p0 += re * pe[0] + ro * po[0];
    p1 += re * pe[1] + ro * po[1];
    p2 += re * pe[2] + ro * po[2];
    p3 += re * pe[3] + ro * po[3];
  }
  float t0 = tanhf(p0) * 0.125f;
  float t1 = tanhf(p1) * 0.125f;
  float t2 = tanhf(p2) * 0.125f;
  float t3 = tanhf(p3) * 0.125f;
  float lg[16];
  float mx = -1e30f;
  #pragma unroll
  for (int r = 0; r < 16; ++r) {
    float s = ((r & 8) ? t0 : -t0) + ((r & 4) ? t1 : -t1) +
              ((r & 2) ? t2 : -t2) + ((r & 1) ? t3 : -t3);
    lg[r] = s;
    mx = fmaxf(mx, s);
  }
  float sum = 0.f;
  #pragma unroll
  for (int r = 0; r < 16; ++r) {
    float e = expf(lg[r] - mx);
    lg[r] = e;
    sum += e;
  }
  float inv = 1.f / sum;
  float* dst = (w ? pq : pk) + ((size_t)mn * T_SEQ + t) * 64 + l * 16;
  #pragma unroll
  for (int r = 0; r < 16; ++r) dst[r] = lg[r] * inv;
}

// ---------------- RACE pass 1: per-chunk sums ----------------
__global__ __launch_bounds__(256) void race_chunksum(const float* __restrict__ pk_g,
                                                     const float* __restrict__ v_g,
                                                     float* __restrict__ csA,
                                                     float* __restrict__ csB) {
  int mn = blockIdx.x, ch = blockIdx.y;
  int n = mn % NHEAD;
  int tid = threadIdx.x;
  int d = tid & 63, g = tid >> 6;
  __shared__ float pk[64], vv[64];
  float a[16], bp[16];
  #pragma unroll
  for (int i = 0; i < 16; ++i) { a[i] = 0.f; bp[i] = 0.f; }
  const float* pkrow = pk_g + ((size_t)mn * T_SEQ + (size_t)ch * TL) * 64;
  const float* vrow = v_g + (size_t)(ch * TL) * QKVW + n * 64;
  for (int t = 0; t < TL; ++t) {
    if (tid < 64) pk[tid] = pkrow[t * 64 + tid];
    else if (tid < 128) vv[tid - 64] = vrow[(size_t)t * QKVW + tid - 64];
    __syncthreads();
    float vd = vv[d];
    #pragma unroll
    for (int i = 0; i < 16; ++i) {
      float p = pk[g * 16 + i];
      a[i] += p;
      bp[i] = fmaf(p, vd, bp[i]);
    }
    __syncthreads();
  }
  size_t base = ((size_t)mn * NCH + ch) * 64;
  if (d == 0) {
    #pragma unroll
    for (int i = 0; i < 16; ++i) csA[base + g * 16 + i] = a[i];
  }
  #pragma unroll
  for (int i = 0; i < 16; ++i) csB[(base + g * 16 + i) * 64 + d] = bp[i];
}

// ---------------- RACE pass 2: exclusive scan over chunks ----------------
__global__ __launch_bounds__(64) void race_chunkscan(float* __restrict__ csA,
                                                     float* __restrict__ csB) {
  int mn = blockIdx.x, lr = blockIdx.y;
  int d = threadIdx.x;
  float runB = 0.f, runA = 0.f;
  for (int c = 0; c < NCH; ++c) {
    size_t ib = (((size_t)mn * NCH + c) * 64 + lr) * 64 + d;
    float b = csB[ib];
    csB[ib] = runB;
    runB += b;
    if (d == 0) {
      size_t ia = ((size_t)mn * NCH + c) * 64 + lr;
      float av = csA[ia];
      csA[ia] = runA;
      runA += av;
    }
  }
}

// ---------------- RACE pass 3: seeded scan + emit (both copies, bf16 out) ---
// grid (12, NCH). ro flat index = n*65536 + t*64 + d (reference scramble).
__global__ __launch_bounds__(256) void race_scan_emit(const float* __restrict__ pk_g,
                                                      const float* __restrict__ pq_g,
                                                      const float* __restrict__ v_g,
                                                      const float* __restrict__ csA,
                                                      const float* __restrict__ csB,
                                                      short* __restrict__ ro) {
  int n = blockIdx.x, ch = blockIdx.y;
  int tid = threadIdx.x;
  int d = tid & 63, g = tid >> 6;
  int mn0 = n, mn1 = NHEAD + n;
  __shared__ float pk0[64], pk1[64], pq0[64], pq1[64], vv[64];
  __shared__ float part[4][64];
  float a0[16], b0[16], a1[16], b1[16];
  size_t base0 = ((size_t)mn0 * NCH + ch) * 64;
  size_t base1 = ((size_t)mn1 * NCH + ch) * 64;
  #pragma unroll
  for (int i = 0; i < 16; ++i) {
    a0[i] = csA[base0 + g * 16 + i];
    b0[i] = csB[(base0 + g * 16 + i) * 64 + d];
    a1[i] = csA[base1 + g * 16 + i];
    b1[i] = csB[(base1 + g * 16 + i) * 64 + d];
  }
  const float* pk0r = pk_g + ((size_t)mn0 * T_SEQ + (size_t)ch * TL) * 64;
  const float* pk1r = pk_g + ((size_t)mn1 * T_SEQ + (size_t)ch * TL) * 64;
  const float* pq0r = pq_g + ((size_t)mn0 * T_SEQ + (size_t)ch * TL) * 64;
  const float* pq1r = pq_g + ((size_t)mn1 * T_SEQ + (size_t)ch * TL) * 64;
  const float* vrow = v_g + (size_t)(ch * TL) * QKVW + n * 64;
  for (int t = 0; t < TL; ++t) {
    if (g == 0) { pk0[d] = pk0r[t * 64 + d]; vv[d] = vrow[(size_t)t * QKVW + d]; }
    else if (g == 1) pk1[d] = pk1r[t * 64 + d];
    else if (g == 2) pq0[d] = pq0r[t * 64 + d];
    else pq1[d] = pq1r[t * 64 + d];
    __syncthreads();
    float vd = vv[d];
    float c = 0.f;
    #pragma unroll
    for (int i = 0; i < 16; ++i) {
      int lr = g * 16 + i;
      float p = pk0[lr];
      a0[i] += p;
      b0[i] = fmaf(p, vd, b0[i]);
      c = fmaf(pq0[lr] * b0[i], __builtin_amdgcn_rcpf(a0[i] + 1e-6f), c);
      p = pk1[lr];
      a1[i] += p;
      b1[i] = fmaf(p, vd, b1[i]);
      c = fmaf(pq1[lr] * b1[i], __builtin_amdgcn_rcpf(a1[i] + 1e-6f), c);
    }
    part[g][d] = c;
    __syncthreads();
    if (tid < 64) {
      float s = part[0][tid] + part[1][tid] + part[2][tid] + part[3][tid];
      ro[n * (T_SEQ * 64) + (ch * TL + t) * 64 + tid] = f2bf(0.5f * s);
    }
  }
}

// ---------------- silu(g1)*g2 -> bf16 ----------------
__global__ __launch_bounds__(256) void silu_mul_k(const float* __restrict__ G,
                                                  short* __restrict__ out) {
  int row = blockIdx.x;
  const float* g1 = G + (size_t)row * (2 * HID_DIM);
  const float* g2 = g1 + HID_DIM;
  for (int i = threadIdx.x; i < HID_DIM; i += 256) {
    float a = g1[i];
    float b = g2[i];
    out[(size_t)row * HID_DIM + i] = f2bf((a / (1.f + expf(-a))) * b);
  }
}

extern "C" void kernel_launch(void* const* d_in, const int* in_sizes, int n_in,
                              void* d_out, int out_size, void* d_ws, size_t ws_size,
                              hipStream_t stream) {
  const int*   in_idx       = (const int*)d_in[0];
  const float* tok_emb      = (const float*)d_in[1];
  const float* norm1_w      = (const float*)d_in[2];
  const float* qw           = (const float*)d_in[3];
  const float* kw           = (const float*)d_in[4];
  const float* vw           = (const float*)d_in[5];
  const float* ow           = (const float*)d_in[6];
  const float* ob           = (const float*)d_in[7];
  const float* norm2_w      = (const float*)d_in[8];
  const float* ff_w1        = (const float*)d_in[9];
  const float* ff_w2        = (const float*)d_in[10];
  const float* ff_w3        = (const float*)d_in[11];
  const float* final_norm_w = (const float*)d_in[12];
  const float* out_w        = (const float*)d_in[13];
  const float* planes       = (const float*)d_in[14];

  float* ws = (float*)d_ws;
  const size_t SZ_TD = (size_t)T_SEQ * D_MODEL;          // 786432
  float* X   = ws;                                       // 786432
  float* STC = X + SZ_TD;                                // 65536
  float* S   = STC + 65536;                              // scratch base
  // phase A (attention)
  short* HbB = (short*)S;                                // 786432 sh = 393216 f
  float* QKV = S + 393216;                               // 1024*2304
  float* PK  = QKV + (size_t)T_SEQ * QKVW;               // 1572864
  float* PQ  = PK + (size_t)MCOPY * NHEAD * T_SEQ * 64;  // 1572864
  float* CSA = PQ + (size_t)MCOPY * NHEAD * T_SEQ * 64;  // 49152
  float* CSB = CSA + (size_t)MCOPY * NHEAD * NCH * 64;   // 3145728
  short* ROb = (short*)(CSB + (size_t)MCOPY * NHEAD * NCH * 64 * 64); // 393216 f
  // phase B (FF) — overlays QKV..CSB (dead by then)
  float* G   = S + 393216;                               // 1024*6144
  short* G1B = (short*)(G + (size_t)T_SEQ * 2 * HID_DIM);// 393216 f
  // bf16 transposed weights
  short* WB = (short*)(S + 9486336);
  const size_t SQ_W = (size_t)D_MODEL * D_MODEL;
  const size_t FF_W = (size_t)D_MODEL * HID_DIM;
  const size_t LAYER_W = 4 * SQ_W + 3 * FF_W;
  short* qkvT[NLAYER]; short* owT[NLAYER]; short* f12T[NLAYER]; short* f3T[NLAYER];
  for (int l = 0; l < NLAYER; ++l) {
    short* base = WB + l * LAYER_W;
    qkvT[l] = base;                  // q|k|v adjacent: [2304][768]
    owT[l]  = base + 3 * SQ_W;
    f12T[l] = base + 4 * SQ_W;       // f1|f2 adjacent: [6144][768]
    f3T[l]  = base + 4 * SQ_W + 2 * FF_W;
  }
  short* outT = WB + NLAYER * LAYER_W;                   // [32000][768]

  stc_k<<<T_SEQ, 64, 0, stream>>>(STC);
  dim3 tb(32, 8);
  for (int l = 0; l < NLAYER; ++l) {
    transpose_cvt<<<dim3(D_MODEL / 32, D_MODEL / 32), tb, 0, stream>>>(qw + l * SQ_W, qkvT[l], D_MODEL, D_MODEL);
    transpose_cvt<<<dim3(D_MODEL / 32, D_MODEL / 32), tb, 0, stream>>>(kw + l * SQ_W, qkvT[l] + SQ_W, D_MODEL, D_MODEL);
    transpose_cvt<<<dim3(D_MODEL / 32, D_MODEL / 32), tb, 0, stream>>>(vw + l * SQ_W, qkvT[l] + 2 * SQ_W, D_MODEL, D_MODEL);
    transpose_cvt<<<dim3(D_MODEL / 32, D_MODEL / 32), tb, 0, stream>>>(ow + l * SQ_W, owT[l], D_MODEL, D_MODEL);
    transpose_cvt<<<dim3(HID_DIM / 32, D_MODEL / 32), tb, 0, stream>>>(ff_w1 + l * FF_W, f12T[l], D_MODEL, HID_DIM);
    transpose_cvt<<<dim3(HID_DIM / 32, D_MODEL / 32), tb, 0, stream>>>(ff_w2 + l * FF_W, f12T[l] + FF_W, D_MODEL, HID_DIM);
    transpose_cvt<<<dim3(D_MODEL / 32, HID_DIM / 32), tb, 0, stream>>>(ff_w3 + l * FF_W, f3T[l], HID_DIM, D_MODEL);
  }
  transpose_cvt<<<dim3(VSIZE / 32, D_MODEL / 32), tb, 0, stream>>>(out_w, outT, D_MODEL, VSIZE);

  embed_k<<<T_SEQ, 256, 0, stream>>>(in_idx, tok_emb, X);

  for (int l = 0; l < NLAYER; ++l) {
    rmsnorm_k<<<T_SEQ, 256, 0, stream>>>(X, norm1_w + l * D_MODEL, HbB);
    gemm_bf16<<<8 * (QKVW / 128), 256, 0, stream>>>(HbB, qkvT[l], nullptr, nullptr, QKV, QKVW, D_MODEL);
    race_probs<<<(MCOPY * NHEAD * T_SEQ * 4 * 2) / 256, 256, 0, stream>>>(
        QKV, STC, planes + (size_t)l * MCOPY * 64 * 16, PQ, PK);
    dim3 gscan(MCOPY * NHEAD, NCH);
    race_chunksum<<<gscan, 256, 0, stream>>>(PK, QKV + 2 * D_MODEL, CSA, CSB);
    dim3 gcs(MCOPY * NHEAD, 64);
    race_chunkscan<<<gcs, 64, 0, stream>>>(CSA, CSB);
    dim3 gemit(NHEAD, NCH);
    race_scan_emit<<<gemit, 256, 0, stream>>>(PK, PQ, QKV + 2 * D_MODEL, CSA, CSB, ROb);
    gemm_bf16<<<8 * (D_MODEL / 128), 256, 0, stream>>>(ROb, owT[l], ob + l * D_MODEL, X, X, D_MODEL, D_MODEL);
    rmsnorm_k<<<T_SEQ, 256, 0, stream>>>(X, norm2_w + l * D_MODEL, HbB);
    gemm_bf16<<<8 * (2 * HID_DIM / 128), 256, 0, stream>>>(HbB, f12T[l], nullptr, nullptr, G, 2 * HID_DIM, D_MODEL);
    silu_mul_k<<<T_SEQ, 256, 0, stream>>>(G, G1B);
    gemm_bf16<<<8 * (D_MODEL / 128), 256, 0, stream>>>(G1B, f3T[l], nullptr, X, X, D_MODEL, HID_DIM);
  }
  rmsnorm_k<<<T_SEQ, 256, 0, stream>>>(X, final_norm_w, HbB);
  gemm_bf16<<<8 * (VSIZE / 128), 256, 0, stream>>>(HbB, outT, nullptr, nullptr, (float*)d_out, VSIZE, D_MODEL);
}

// Round 5
// 527.113 us; speedup vs baseline: 6.4443x; 1.2901x over previous
//
#include <hip/hip_runtime.h>
#include <hip/hip_bf16.h>

#define T_SEQ 1024
#define D_MODEL 768
#define QKVW 2304
#define NHEAD 12
#define NLAYER 2
#define MCOPY 2
#define HID_DIM 3072
#define VSIZE 32000
#define NCH 32
#define TL 32

typedef __attribute__((ext_vector_type(8))) short short8;
typedef __attribute__((ext_vector_type(4))) float f32x4;

__device__ __forceinline__ short f2bf(float f) {
  unsigned u = __builtin_bit_cast(unsigned, f);
  u = (u + 0x7FFFu + ((u >> 16) & 1u)) >> 16;   // RNE
  return (short)u;
}

// ---------------- sin/cos table: stc[t][i] = (cos, sin) ----------------
__global__ __launch_bounds__(64) void stc_k(float* __restrict__ stc) {
  int t = blockIdx.x;
  int i = threadIdx.x;
  if (i < 32) {
    float theta = powf(10000.0f, -(float)i / 32.0f);
    float s, c;
    sincosf((float)t * theta, &s, &c);
    stc[t * 64 + 2 * i] = c;
    stc[t * 64 + 2 * i + 1] = s;
  }
}

// ---------------- embedding gather ----------------
__global__ __launch_bounds__(256) void embed_k(const int* __restrict__ idx,
                                               const float* __restrict__ emb,
                                               float* __restrict__ x) {
  int t = blockIdx.x;
  int r = idx[t];
  for (int d = threadIdx.x; d < D_MODEL; d += 256)
    x[t * D_MODEL + d] = emb[r * D_MODEL + d];
}

// ------- fused: X += sum(parts) (+bias); out = rmsnorm(X)*w -> bf16 -------
__global__ __launch_bounds__(256) void add_norm_k(float* __restrict__ x,
                                                  const float* __restrict__ parts,
                                                  int nparts,
                                                  const float* __restrict__ bias,
                                                  const float* __restrict__ w,
                                                  short* __restrict__ out) {
  int t = blockIdx.x, tid = threadIdx.x;
  float v[3];
  float ss = 0.f;
  #pragma unroll
  for (int j = 0; j < 3; ++j) {
    int i = tid + j * 256;
    float val = x[(size_t)t * D_MODEL + i];
    if (bias) val += bias[i];
    for (int p = 0; p < nparts; ++p)
      val += parts[(size_t)p * (T_SEQ * D_MODEL) + (size_t)t * D_MODEL + i];
    v[j] = val;
    ss += val * val;
  }
  __shared__ float red[256];
  red[tid] = ss; __syncthreads();
  for (int s = 128; s > 0; s >>= 1) {
    if (tid < s) red[tid] += red[tid + s];
    __syncthreads();
  }
  float inv = rsqrtf(red[0] / (float)D_MODEL + 1e-5f);
  #pragma unroll
  for (int j = 0; j < 3; ++j) {
    int i = tid + j * 256;
    if (nparts || bias) x[(size_t)t * D_MODEL + i] = v[j];
    out[(size_t)t * D_MODEL + i] = f2bf(v[j] * inv * w[i]);
  }
}

// ---------------- weight transpose + f32->bf16: W[K][N] -> WT[N][K] ---------
__global__ __launch_bounds__(256) void transpose_cvt(const float* __restrict__ W,
                                                     short* __restrict__ WT,
                                                     int K, int N) {
  __shared__ float tile[32][33];
  int tx = threadIdx.x, ty = threadIdx.y;     // block (32,8)
  int n0 = blockIdx.x * 32, k0 = blockIdx.y * 32;
  #pragma unroll
  for (int i = 0; i < 4; ++i)
    tile[ty + 8 * i][tx] = W[(size_t)(k0 + ty + 8 * i) * N + n0 + tx];
  __syncthreads();
  #pragma unroll
  for (int i = 0; i < 4; ++i)
    WT[(size_t)(n0 + ty + 8 * i) * K + k0 + tx] = f2bf(tile[tx][ty + 8 * i]);
}

// --- ff12 interleaved transpose: row n -> (n&16 ? w2 : w1) col (n>>5)*16+(n&15)
__global__ __launch_bounds__(256) void transpose_cvt_ff12(const float* __restrict__ W1,
                                                          const float* __restrict__ W2,
                                                          short* __restrict__ WT) {
  __shared__ float tile[32][33];
  int tx = threadIdx.x, ty = threadIdx.y;     // block (32,8)
  int n0 = blockIdx.x * 32, k0 = blockIdx.y * 32;
  int h0 = n0 >> 1;
  const float* src = (tx < 16) ? (W1 + h0 + tx) : (W2 + h0 + (tx - 16));
  #pragma unroll
  for (int i = 0; i < 4; ++i)
    tile[ty + 8 * i][tx] = src[(size_t)(k0 + ty + 8 * i) * HID_DIM];
  __syncthreads();
  #pragma unroll
  for (int i = 0; i < 4; ++i) {
    int n = ty + 8 * i;
    WT[(size_t)(n0 + n) * D_MODEL + k0 + tx] = f2bf(tile[tx][n]);
  }
}

// ---------------- bf16 MFMA GEMM core ----------------
// A: [1024][K] bf16. Bt: [N][K] bf16. 128x128 tile, BK=64, 4 waves.
// MODE 0: Cf[row][col] = acc                    (QKV, head)
// MODE 1: Cf[z*1024*N + row][col] = acc         (split-K partials; z=blockIdx.y)
// MODE 2: Cs[row][h] = bf16(silu(g1)*g2)        (fused FF12, interleaved cols)
__device__ __forceinline__ void stage_tile(const short* __restrict__ gbase,
                                           int ldK, short* lds, int tid) {
  #pragma unroll
  for (int j = 0; j < 4; ++j) {
    int r = j * 32 + (tid >> 3);
    int s = tid & 7;
    const short* gp = gbase + (size_t)r * ldK + (((s ^ (r & 7))) << 3);
    short* lp = lds + j * 2048 + tid * 8;
    __builtin_amdgcn_global_load_lds((const __attribute__((address_space(1))) void*)gp,
                                     (__attribute__((address_space(3))) void*)lp,
                                     16, 0, 0);
  }
}

__device__ __forceinline__ short8 frag_ld(const short* lds, int row, int sl) {
  return *(const short8*)(lds + row * 64 + ((sl ^ (row & 7)) << 3));
}

template<int MODE>
__global__ __launch_bounds__(256) void gemm_t(const short* __restrict__ A,
                                              const short* __restrict__ Bt,
                                              float* __restrict__ Cf,
                                              short* __restrict__ Cs,
                                              int N, int K) {
  __shared__ short As[128 * 64];
  __shared__ short Bs[128 * 64];
  int tid = threadIdx.x;
  int lane = tid & 63;
  int wave = tid >> 6;
  int wr = wave >> 1, wc = wave & 1;
  int l15 = lane & 15, kg = lane >> 4;

  int cpx = gridDim.x >> 3;
  int wg = (blockIdx.x & 7) * cpx + (blockIdx.x >> 3);
  int row0 = (wg & 7) * 128;
  int col0 = (wg >> 3) * 128;

  int kn = K / gridDim.y;
  int koff = blockIdx.y * kn;
  const short* Ab = A + (size_t)row0 * K + koff;
  const short* Bb = Bt + (size_t)col0 * K + koff;
  int nt = kn >> 6;

  f32x4 acc[4][4] = {};

  for (int t = 0; t < nt; ++t) {
    stage_tile(Ab + t * 64, K, As, tid);
    stage_tile(Bb + t * 64, K, Bs, tid);
    __syncthreads();
    #pragma unroll
    for (int kk = 0; kk < 2; ++kk) {
      short8 af[4], bf4[4];
      #pragma unroll
      for (int m = 0; m < 4; ++m)
        af[m] = frag_ld(As, wr * 64 + m * 16 + l15, 4 * kk + kg);
      #pragma unroll
      for (int n = 0; n < 4; ++n)
        bf4[n] = frag_ld(Bs, wc * 64 + n * 16 + l15, 4 * kk + kg);
      #pragma unroll
      for (int m = 0; m < 4; ++m)
        #pragma unroll
        for (int n = 0; n < 4; ++n)
          acc[m][n] = __builtin_amdgcn_mfma_f32_16x16x32_bf16(af[m], bf4[n], acc[m][n], 0, 0, 0);
    }
    __syncthreads();
  }

  int rbase = (lane >> 4) * 4;
  if constexpr (MODE == 2) {
    int base = col0 + wc * 64;
    #pragma unroll
    for (int p = 0; p < 2; ++p) {
      int h = (base >> 1) + p * 16 + l15;
      #pragma unroll
      for (int m = 0; m < 4; ++m) {
        #pragma unroll
        for (int r = 0; r < 4; ++r) {
          int row = row0 + wr * 64 + m * 16 + rbase + r;
          float g1 = acc[m][2 * p][r];
          float g2 = acc[m][2 * p + 1][r];
          Cs[(size_t)row * HID_DIM + h] = f2bf((g1 / (1.f + expf(-g1))) * g2);
        }
      }
    }
  } else {
    float* Co = Cf;
    if constexpr (MODE == 1) Co += (size_t)blockIdx.y * T_SEQ * N;
    #pragma unroll
    for (int n = 0; n < 4; ++n) {
      int col = col0 + wc * 64 + n * 16 + l15;
      #pragma unroll
      for (int m = 0; m < 4; ++m) {
        #pragma unroll
        for (int r = 0; r < 4; ++r) {
          int row = row0 + wr * 64 + m * 16 + rbase + r;
          Co[(size_t)row * N + col] = acc[m][n][r];
        }
      }
    }
  }
}

// ---------------- RACE probs with fused RoPE ----------------
__global__ __launch_bounds__(256) void race_probs(const float* __restrict__ qkv,
                                                  const float* __restrict__ stc,
                                                  const float* __restrict__ planes,
                                                  float* __restrict__ pq,
                                                  float* __restrict__ pk) {
  int gid = blockIdx.x * 256 + threadIdx.x;
  int w = gid & 1;
  int l = (gid >> 1) & 3;
  int t = (gid >> 3) & 1023;
  int mn = gid >> 13;
  int m = mn / NHEAD, n = mn % NHEAD;
  const float* raw = qkv + (size_t)t * QKVW + (w ? 0 : D_MODEL) + n * 64;
  const float* sc = stc + t * 64;
  const float* pl = planes + m * 64 * 16 + l * 4;
  float p0 = 0.f, p1 = 0.f, p2 = 0.f, p3 = 0.f;
  #pragma unroll 4
  for (int i = 0; i < 32; ++i) {
    float e = raw[2 * i], o = raw[2 * i + 1];
    float c = sc[2 * i], s = sc[2 * i + 1];
    float re = e * c - o * s;
    float ro = e * s + o * c;
    const float* pe = pl + i * 16;
    const float* po = pl + (i + 32) * 16;
    p0 += re * pe[0] + ro * po[0];
    p1 += re * pe[1] + ro * po[1];
    p2 += re * pe[2] + ro * po[2];
    p3 += re * pe[3] + ro * po[3];
  }
  float t0 = tanhf(p0) * 0.125f;
  float t1 = tanhf(p1) * 0.125f;
  float t2 = tanhf(p2) * 0.125f;
  float t3 = tanhf(p3) * 0.125f;
  float lg[16];
  float mx = -1e30f;
  #pragma unroll
  for (int r = 0; r < 16; ++r) {
    float s = ((r & 8) ? t0 : -t0) + ((r & 4) ? t1 : -t1) +
              ((r & 2) ? t2 : -t2) + ((r & 1) ? t3 : -t3);
    lg[r] = s;
    mx = fmaxf(mx, s);
  }
  float sum = 0.f;
  #pragma unroll
  for (int r = 0; r < 16; ++r) {
    float e = expf(lg[r] - mx);
    lg[r] = e;
    sum += e;
  }
  float inv = 1.f / sum;
  float* dst = (w ? pq : pk) + ((size_t)mn * T_SEQ + t) * 64 + l * 16;
  #pragma unroll
  for (int r = 0; r < 16; ++r) dst[r] = lg[r] * inv;
}

// ---------------- RACE pass 1: per-chunk sums ----------------
__global__ __launch_bounds__(256) void race_chunksum(const float* __restrict__ pk_g,
                                                     const float* __restrict__ v_g,
                                                     float* __restrict__ csA,
                                                     float* __restrict__ csB) {
  int mn = blockIdx.x, ch = blockIdx.y;
  int n = mn % NHEAD;
  int tid = threadIdx.x;
  int d = tid & 63, g = tid >> 6;
  __shared__ float pk[64], vv[64];
  float a[16], bp[16];
  #pragma unroll
  for (int i = 0; i < 16; ++i) { a[i] = 0.f; bp[i] = 0.f; }
  const float* pkrow = pk_g + ((size_t)mn * T_SEQ + (size_t)ch * TL) * 64;
  const float* vrow = v_g + (size_t)(ch * TL) * QKVW + n * 64;
  for (int t = 0; t < TL; ++t) {
    if (tid < 64) pk[tid] = pkrow[t * 64 + tid];
    else if (tid < 128) vv[tid - 64] = vrow[(size_t)t * QKVW + tid - 64];
    __syncthreads();
    float vd = vv[d];
    #pragma unroll
    for (int i = 0; i < 16; ++i) {
      float p = pk[g * 16 + i];
      a[i] += p;
      bp[i] = fmaf(p, vd, bp[i]);
    }
    __syncthreads();
  }
  size_t base = ((size_t)mn * NCH + ch) * 64;
  if (d == 0) {
    #pragma unroll
    for (int i = 0; i < 16; ++i) csA[base + g * 16 + i] = a[i];
  }
  #pragma unroll
  for (int i = 0; i < 16; ++i) csB[(base + g * 16 + i) * 64 + d] = bp[i];
}

// ---------------- RACE pass 2: exclusive scan over chunks ----------------
__global__ __launch_bounds__(64) void race_chunkscan(float* __restrict__ csA,
                                                     float* __restrict__ csB) {
  int mn = blockIdx.x, lr = blockIdx.y;
  int d = threadIdx.x;
  float runB = 0.f, runA = 0.f;
  for (int c = 0; c < NCH; ++c) {
    size_t ib = (((size_t)mn * NCH + c) * 64 + lr) * 64 + d;
    float b = csB[ib];
    csB[ib] = runB;
    runB += b;
    if (d == 0) {
      size_t ia = ((size_t)mn * NCH + c) * 64 + lr;
      float av = csA[ia];
      csA[ia] = runA;
      runA += av;
    }
  }
}

// ---------------- RACE pass 3: seeded scan + emit (both copies, bf16 out) ---
__global__ __launch_bounds__(256) void race_scan_emit(const float* __restrict__ pk_g,
                                                      const float* __restrict__ pq_g,
                                                      const float* __restrict__ v_g,
                                                      const float* __restrict__ csA,
                                                      const float* __restrict__ csB,
                                                      short* __restrict__ ro) {
  int n = blockIdx.x, ch = blockIdx.y;
  int tid = threadIdx.x;
  int d = tid & 63, g = tid >> 6;
  int mn0 = n, mn1 = NHEAD + n;
  __shared__ float pk0[64], pk1[64], pq0[64], pq1[64], vv[64];
  __shared__ float part[4][64];
  float a0[16], b0[16], a1[16], b1[16];
  size_t base0 = ((size_t)mn0 * NCH + ch) * 64;
  size_t base1 = ((size_t)mn1 * NCH + ch) * 64;
  #pragma unroll
  for (int i = 0; i < 16; ++i) {
    a0[i] = csA[base0 + g * 16 + i];
    b0[i] = csB[(base0 + g * 16 + i) * 64 + d];
    a1[i] = csA[base1 + g * 16 + i];
    b1[i] = csB[(base1 + g * 16 + i) * 64 + d];
  }
  const float* pk0r = pk_g + ((size_t)mn0 * T_SEQ + (size_t)ch * TL) * 64;
  const float* pk1r = pk_g + ((size_t)mn1 * T_SEQ + (size_t)ch * TL) * 64;
  const float* pq0r = pq_g + ((size_t)mn0 * T_SEQ + (size_t)ch * TL) * 64;
  const float* pq1r = pq_g + ((size_t)mn1 * T_SEQ + (size_t)ch * TL) * 64;
  const float* vrow = v_g + (size_t)(ch * TL) * QKVW + n * 64;
  for (int t = 0; t < TL; ++t) {
    if (g == 0) { pk0[d] = pk0r[t * 64 + d]; vv[d] = vrow[(size_t)t * QKVW + d]; }
    else if (g == 1) pk1[d] = pk1r[t * 64 + d];
    else if (g == 2) pq0[d] = pq0r[t * 64 + d];
    else pq1[d] = pq1r[t * 64 + d];
    __syncthreads();
    float vd = vv[d];
    float c = 0.f;
    #pragma unroll
    for (int i = 0; i < 16; ++i) {
      int lr = g * 16 + i;
      float p = pk0[lr];
      a0[i] += p;
      b0[i] = fmaf(p, vd, b0[i]);
      c = fmaf(pq0[lr] * b0[i], __builtin_amdgcn_rcpf(a0[i] + 1e-6f), c);
      p = pk1[lr];
      a1[i] += p;
      b1[i] = fmaf(p, vd, b1[i]);
      c = fmaf(pq1[lr] * b1[i], __builtin_amdgcn_rcpf(a1[i] + 1e-6f), c);
    }
    part[g][d] = c;
    __syncthreads();
    if (tid < 64) {
      float s = part[0][tid] + part[1][tid] + part[2][tid] + part[3][tid];
      ro[n * (T_SEQ * 64) + (ch * TL + t) * 64 + tid] = f2bf(0.5f * s);
    }
  }
}

extern "C" void kernel_launch(void* const* d_in, const int* in_sizes, int n_in,
                              void* d_out, int out_size, void* d_ws, size_t ws_size,
                              hipStream_t stream) {
  const int*   in_idx       = (const int*)d_in[0];
  const float* tok_emb      = (const float*)d_in[1];
  const float* norm1_w      = (const float*)d_in[2];
  const float* qw           = (const float*)d_in[3];
  const float* kw           = (const float*)d_in[4];
  const float* vw           = (const float*)d_in[5];
  const float* ow           = (const float*)d_in[6];
  const float* ob           = (const float*)d_in[7];
  const float* norm2_w      = (const float*)d_in[8];
  const float* ff_w1        = (const float*)d_in[9];
  const float* ff_w2        = (const float*)d_in[10];
  const float* ff_w3        = (const float*)d_in[11];
  const float* final_norm_w = (const float*)d_in[12];
  const float* out_w        = (const float*)d_in[13];
  const float* planes       = (const float*)d_in[14];

  float* ws = (float*)d_ws;
  const size_t SZ_TD = (size_t)T_SEQ * D_MODEL;          // 786432
  float* X   = ws;
  float* STC = X + SZ_TD;
  float* S   = STC + 65536;
  // S-region layout (identical footprint to prev round):
  short* HbB = (short*)S;                                // 393216 f
  float* QKV = S + 393216;                               // 2359296 f
  float* PK  = QKV + (size_t)T_SEQ * QKVW;               // 1572864 f
  float* PQ  = PK + (size_t)MCOPY * NHEAD * T_SEQ * 64;  // 1572864 f
  float* CSA = PQ + (size_t)MCOPY * NHEAD * T_SEQ * 64;  // 49152 f
  float* CSB = CSA + (size_t)MCOPY * NHEAD * NCH * 64;   // 3145728 f
  short* ROb = (short*)(CSB + (size_t)MCOPY * NHEAD * NCH * 64 * 64); // 393216 f
  // aliases (regions dead at time of use):
  short* G1B = (short*)QKV;                              // FF12 out: 1572864 f
  float* PP  = PK;                                       // split-K partials: 4*786432 f
  // bf16 transposed weights
  short* WB = (short*)(S + 9486336);
  const size_t SQ_W = (size_t)D_MODEL * D_MODEL;
  const size_t FF_W = (size_t)D_MODEL * HID_DIM;
  const size_t LAYER_W = 4 * SQ_W + 3 * FF_W;
  short* qkvT[NLAYER]; short* owT[NLAYER]; short* f12T[NLAYER]; short* f3T[NLAYER];
  for (int l = 0; l < NLAYER; ++l) {
    short* base = WB + l * LAYER_W;
    qkvT[l] = base;                  // [2304][768]
    owT[l]  = base + 3 * SQ_W;       // [768][768]
    f12T[l] = base + 4 * SQ_W;       // [6144][768] interleaved w1/w2
    f3T[l]  = base + 4 * SQ_W + 2 * FF_W;  // [768][3072]
  }
  short* outT = WB + NLAYER * LAYER_W;                   // [32000][768]

  stc_k<<<T_SEQ, 64, 0, stream>>>(STC);
  dim3 tb(32, 8);
  for (int l = 0; l < NLAYER; ++l) {
    transpose_cvt<<<dim3(D_MODEL / 32, D_MODEL / 32), tb, 0, stream>>>(qw + l * SQ_W, qkvT[l], D_MODEL, D_MODEL);
    transpose_cvt<<<dim3(D_MODEL / 32, D_MODEL / 32), tb, 0, stream>>>(kw + l * SQ_W, qkvT[l] + SQ_W, D_MODEL, D_MODEL);
    transpose_cvt<<<dim3(D_MODEL / 32, D_MODEL / 32), tb, 0, stream>>>(vw + l * SQ_W, qkvT[l] + 2 * SQ_W, D_MODEL, D_MODEL);
    transpose_cvt<<<dim3(D_MODEL / 32, D_MODEL / 32), tb, 0, stream>>>(ow + l * SQ_W, owT[l], D_MODEL, D_MODEL);
    transpose_cvt_ff12<<<dim3(2 * HID_DIM / 32, D_MODEL / 32), tb, 0, stream>>>(
        ff_w1 + l * FF_W, ff_w2 + l * FF_W, f12T[l]);
    transpose_cvt<<<dim3(D_MODEL / 32, HID_DIM / 32), tb, 0, stream>>>(ff_w3 + l * FF_W, f3T[l], HID_DIM, D_MODEL);
  }
  transpose_cvt<<<dim3(VSIZE / 32, D_MODEL / 32), tb, 0, stream>>>(out_w, outT, D_MODEL, VSIZE);

  embed_k<<<T_SEQ, 256, 0, stream>>>(in_idx, tok_emb, X);
  add_norm_k<<<T_SEQ, 256, 0, stream>>>(X, nullptr, 0, nullptr, norm1_w, HbB);

  for (int l = 0; l < NLAYER; ++l) {
    gemm_t<0><<<dim3(8 * (QKVW / 128), 1), 256, 0, stream>>>(HbB, qkvT[l], QKV, nullptr, QKVW, D_MODEL);
    race_probs<<<(MCOPY * NHEAD * T_SEQ * 4 * 2) / 256, 256, 0, stream>>>(
        QKV, STC, planes + (size_t)l * MCOPY * 64 * 16, PQ, PK);
    dim3 gscan(MCOPY * NHEAD, NCH);
    race_chunksum<<<gscan, 256, 0, stream>>>(PK, QKV + 2 * D_MODEL, CSA, CSB);
    dim3 gcs(MCOPY * NHEAD, 64);
    race_chunkscan<<<gcs, 64, 0, stream>>>(CSA, CSB);
    dim3 gemit(NHEAD, NCH);
    race_scan_emit<<<gemit, 256, 0, stream>>>(PK, PQ, QKV + 2 * D_MODEL, CSA, CSB, ROb);
    // O-proj: split-K=2 partials, then fused add(+ob)+rmsnorm2
    gemm_t<1><<<dim3(8 * (D_MODEL / 128), 2), 256, 0, stream>>>(ROb, owT[l], PP, nullptr, D_MODEL, D_MODEL);
    add_norm_k<<<T_SEQ, 256, 0, stream>>>(X, PP, 2, ob + l * D_MODEL, norm2_w + l * D_MODEL, HbB);
    // FF12 fused with silu (interleaved weights) -> bf16 G1B
    gemm_t<2><<<dim3(8 * (2 * HID_DIM / 128), 1), 256, 0, stream>>>(HbB, f12T[l], nullptr, G1B, 2 * HID_DIM, D_MODEL);
    // FF3: split-K=4 partials, then fused add+next-norm
    gemm_t<1><<<dim3(8 * (D_MODEL / 128), 4), 256, 0, stream>>>(G1B, f3T[l], PP, nullptr, D_MODEL, HID_DIM);
    const float* nw = (l == NLAYER - 1) ? final_norm_w : norm1_w + (l + 1) * D_MODEL;
    add_norm_k<<<T_SEQ, 256, 0, stream>>>(X, PP, 4, nullptr, nw, HbB);
  }
  gemm_t<0><<<dim3(8 * (VSIZE / 128), 1), 256, 0, stream>>>(HbB, outT, (float*)d_out, nullptr, VSIZE, D_MODEL);
}